// Round 3
// baseline (1719.084 us; speedup 1.0000x reference)
//
// LunarisCodex MoE-GPT forward, MI355X/gfx950. Round 3: gemm_h staging via
// global_load_lds (16B direct-to-LDS, m97 pattern) + PV causal K-truncation.
// Precision: split-fp16 x3 upstream (routing-exact); single fp16 logits GEMM.
#include <hip/hip_runtime.h>

typedef __attribute__((ext_vector_type(8))) _Float16 half8;
typedef __attribute__((ext_vector_type(4))) float f32x4;

constexpr int Bc = 2, Tc = 1024, Dc = 768, NHc = 12, HDc = 64;
constexpr int Vc = 50257, Lc = 2, Ec = 8, Hc = 2048;
constexpr int Ntok = Bc * Tc;            // 2048
constexpr int CAPc = 320, CAPPc = 384;   // capacity, padded rows per expert
constexpr long long LOGITS_N = (long long)Bc * Tc * Vc;  // 102926336

typedef const __attribute__((address_space(1))) unsigned int* gas_t;
typedef __attribute__((address_space(3))) unsigned int* las_t;
__device__ __forceinline__ void gload16(const void* g, void* l) {
  __builtin_amdgcn_global_load_lds((gas_t)g, (las_t)l, 16, 0, 0);
}

__device__ __forceinline__ void splitf16(float a, unsigned short& h, unsigned short& l) {
  _Float16 hh = (_Float16)a;                       // RNE
  _Float16 ll = (_Float16)(a - (float)hh);
  h = __builtin_bit_cast(unsigned short, hh);
  l = __builtin_bit_cast(unsigned short, ll);
}
__device__ __forceinline__ unsigned short f16o(float a) {
  _Float16 hh = (_Float16)a;
  return __builtin_bit_cast(unsigned short, hh);
}

// ---------------- small kernels ----------------

__global__ void zero_small(float* psum, float* z2) {
  int t = threadIdx.x;
  if (t < Lc * Ec) psum[t] = 0.f;
  if (t < Lc) z2[t] = 0.f;
}

__global__ void embed_k(const int* __restrict__ idx, const float* __restrict__ wte,
                        float* __restrict__ x) {
  int n = blockIdx.x;
  long long v = idx[n];
  const float4* src = (const float4*)(wte + v * 768);
  float4* dst = (float4*)(x + (long long)n * 768);
  int t = threadIdx.x;
  if (t < 192) dst[t] = src[t];
}

// f32 -> fp16 single (for wte)
__global__ void f2h4(const float* __restrict__ in, unsigned short* __restrict__ out,
                     long long n4) {
  long long i = (long long)blockIdx.x * 256 + threadIdx.x;
  if (i >= n4) return;
  float4 v = ((const float4*)in)[i];
  ushort4 o;
  o.x = f16o(v.x); o.y = f16o(v.y); o.z = f16o(v.z); o.w = f16o(v.w);
  ((ushort4*)out)[i] = o;
}

// f32 (R,K) -> fp16 split (R,2K) [hi K | lo K]
__global__ void __launch_bounds__(256) split2_rows(const float* __restrict__ src,
    unsigned short* __restrict__ dst, int K, long long total4) {
  long long i = (long long)blockIdx.x * 256 + threadIdx.x;
  if (i >= total4) return;
  int kq = (int)(i % (K / 4)) * 4;
  long long row = i / (K / 4);
  float4 v = *(const float4*)(src + row * K + kq);
  ushort4 h, l;
  splitf16(v.x, h.x, l.x); splitf16(v.y, h.y, l.y);
  splitf16(v.z, h.z, l.z); splitf16(v.w, h.w, l.w);
  unsigned short* d = dst + row * 2 * K + kq;
  *(ushort4*)d = h;
  *(ushort4*)(d + K) = l;
}

// f32 weights (K,N) -> fp16 split transposed (N,2K) [hi K | lo K], batched over z
__global__ void __launch_bounds__(256) split2_wT(const float* __restrict__ src,
    unsigned short* __restrict__ dst, int K, int N, long long sS, long long sD) {
  __shared__ float t[32][33];
  int z = blockIdx.z;
  src += (long long)z * sS;
  dst += (long long)z * sD;
  int n0 = blockIdx.x * 32, k0 = blockIdx.y * 32;
  int tid = threadIdx.x;
  int r = tid >> 3, c4 = (tid & 7) * 4;
  float4 v = *(const float4*)(src + (long long)(k0 + r) * N + n0 + c4);
  t[r][c4 + 0] = v.x; t[r][c4 + 1] = v.y; t[r][c4 + 2] = v.z; t[r][c4 + 3] = v.w;
  __syncthreads();
  int n = tid >> 3, kq = (tid & 7) * 4;
  ushort4 h, l;
  splitf16(t[kq + 0][n], h.x, l.x);
  splitf16(t[kq + 1][n], h.y, l.y);
  splitf16(t[kq + 2][n], h.z, l.z);
  splitf16(t[kq + 3][n], h.w, l.w);
  unsigned short* d = dst + (long long)(n0 + n) * 2 * K + k0 + kq;
  *(ushort4*)d = h;
  *(ushort4*)(d + K) = l;
}

// rmsnorm over 768 cols; strided in/out (q,k live inside qkv rows), f32 out
__global__ void __launch_bounds__(256) rmsnorm_k(const float* in, int istride,
                                                 float* outp, int ostride,
                                                 const float* w) {
  long long n = blockIdx.x;
  const float* xr = in + n * istride;
  float* yr = outp + n * ostride;
  int tid = threadIdx.x;
  float s = 0.f;
  for (int i = tid; i < 768; i += 256) { float v = xr[i]; s += v * v; }
  #pragma unroll
  for (int o = 32; o; o >>= 1) s += __shfl_down(s, o);
  __shared__ float red[4];
  __shared__ float bs;
  if ((tid & 63) == 0) red[tid >> 6] = s;
  __syncthreads();
  if (tid == 0) bs = rsqrtf((red[0] + red[1] + red[2] + red[3]) / 768.0f + 1e-5f);
  __syncthreads();
  float sc = bs;
  for (int i = tid; i < 768; i += 256) yr[i] = xr[i] * sc * w[i];
}

// rmsnorm -> fp16 single output (final ln before logits)
__global__ void __launch_bounds__(256) rmsnorm_h(const float* in,
                                                 unsigned short* outp, const float* w) {
  long long n = blockIdx.x;
  const float* xr = in + n * 768;
  unsigned short* yr = outp + n * 768;
  int tid = threadIdx.x;
  float s = 0.f;
  for (int i = tid; i < 768; i += 256) { float v = xr[i]; s += v * v; }
  #pragma unroll
  for (int o = 32; o; o >>= 1) s += __shfl_down(s, o);
  __shared__ float red[4];
  __shared__ float bs;
  if ((tid & 63) == 0) red[tid >> 6] = s;
  __syncthreads();
  if (tid == 0) bs = rsqrtf((red[0] + red[1] + red[2] + red[3]) / 768.0f + 1e-5f);
  __syncthreads();
  float sc = bs;
  for (int i = tid; i < 768; i += 256) yr[i] = f16o(xr[i] * sc * w[i]);
}

// qkv (N,2304) f32 -> split-fp16 qr,kr (z,1024,128=[hi64|lo64]) with RoPE,
// and V transposed vr (z,64,2048=[hi 1024 | lo 1024])
__global__ void __launch_bounds__(256) rope_split(const float* __restrict__ qkv,
    unsigned short* __restrict__ qr, unsigned short* __restrict__ kr,
    unsigned short* __restrict__ vr) {
  int i = blockIdx.x * 256 + threadIdx.x;   // < Ntok*12*32
  int j = i & 31;
  int hh = (i >> 5) % 12;
  int n = i / (32 * 12);
  int t = n & 1023;
  float fr = powf(10000.0f, -((float)(2 * j) * (1.0f / 64.0f)));
  float ang = (float)t * fr;
  float c = cosf(ang), s = sinf(ang);
  const float* bp = qkv + (long long)n * 2304 + hh * 64 + 2 * j;
  int z = (n >> 10) * 12 + hh;
  long long qb = ((long long)z * 1024 + t) * 128 + 2 * j;
  unsigned short h0, l0, h1, l1;
  float q0 = bp[0], q1 = bp[1];
  splitf16(q0 * c - q1 * s, h0, l0);
  splitf16(q0 * s + q1 * c, h1, l1);
  *(unsigned int*)&qr[qb] = (unsigned)h0 | ((unsigned)h1 << 16);
  *(unsigned int*)&qr[qb + 64] = (unsigned)l0 | ((unsigned)l1 << 16);
  float k0 = bp[768], k1 = bp[769];
  splitf16(k0 * c - k1 * s, h0, l0);
  splitf16(k0 * s + k1 * c, h1, l1);
  *(unsigned int*)&kr[qb] = (unsigned)h0 | ((unsigned)h1 << 16);
  *(unsigned int*)&kr[qb + 64] = (unsigned)l0 | ((unsigned)l1 << 16);
  float v0 = bp[1536], v1 = bp[1537];
  splitf16(v0, h0, l0);
  splitf16(v1, h1, l1);
  long long vb = ((long long)z * 64 + 2 * j) * 2048 + t;
  vr[vb] = h0; vr[vb + 1024] = l0;
  vr[vb + 2048] = h1; vr[vb + 3072] = l1;
}

// causal softmax over rows of (z,T,T) f32; writes the row back IN PLACE as
// split-fp16 [hi 1024 | lo 1024] for the PV MFMA GEMM.
__global__ void __launch_bounds__(256) softmax_causal(float* sp) {
  int i = blockIdx.x;
  long long z = blockIdx.y;
  float* row = sp + z * (long long)Tc * Tc + (long long)i * Tc;
  int nv = i + 1;
  __shared__ float buf[1024];
  __shared__ float red[4];
  __shared__ float bval;
  int tid = threadIdx.x;
  float mx = -3.4e38f;
  for (int j = tid; j < nv; j += 256) { float v = row[j] * 0.125f; buf[j] = v; mx = fmaxf(mx, v); }
  #pragma unroll
  for (int o = 32; o; o >>= 1) mx = fmaxf(mx, __shfl_down(mx, o));
  if ((tid & 63) == 0) red[tid >> 6] = mx;
  __syncthreads();
  if (tid == 0) bval = fmaxf(fmaxf(red[0], red[1]), fmaxf(red[2], red[3]));
  __syncthreads();
  float m = bval;
  float s = 0.f;
  for (int j = tid; j < nv; j += 256) { float p = expf(buf[j] - m); buf[j] = p; s += p; }
  #pragma unroll
  for (int o = 32; o; o >>= 1) s += __shfl_down(s, o);
  if ((tid & 63) == 0) red[tid >> 6] = s;
  __syncthreads();
  if (tid == 0) bval = red[0] + red[1] + red[2] + red[3];
  __syncthreads();
  float den = bval;
  unsigned short* rowh = (unsigned short*)row;
  for (int j = tid; j < 1024; j += 256) {
    float p = (j < nv) ? buf[j] / den : 0.f;
    unsigned short h, l;
    splitf16(p, h, l);
    rowh[j] = h;
    rowh[1024 + j] = l;
  }
}

// gate: logits(f32), softmax probs, argmax (first-max), aux accumulators
__global__ void __launch_bounds__(256) gate_k(const float* __restrict__ xin,
    const float* __restrict__ gw, int* __restrict__ top,
    float* __restrict__ psum, float* __restrict__ z2) {
  __shared__ float gws[768 * 8];
  __shared__ float pacc[8];
  __shared__ float zacc;
  int tid = threadIdx.x;
  for (int i = tid; i < 768 * 8 / 4; i += 256) ((float4*)gws)[i] = ((const float4*)gw)[i];
  if (tid < 8) pacc[tid] = 0.f;
  if (tid == 0) zacc = 0.f;
  __syncthreads();
  int n = blockIdx.x * 256 + tid;
  const float4* xr4 = (const float4*)(xin + (long long)n * 768);
  float l[8] = {0, 0, 0, 0, 0, 0, 0, 0};
  for (int d4 = 0; d4 < 192; ++d4) {
    float4 xv = xr4[d4];
    const float* g = &gws[d4 * 32];
    #pragma unroll
    for (int e = 0; e < 8; ++e)
      l[e] += xv.x * g[e] + xv.y * g[8 + e] + xv.z * g[16 + e] + xv.w * g[24 + e];
  }
  float mx = l[0]; int bi = 0;
  #pragma unroll
  for (int e = 1; e < 8; ++e) if (l[e] > mx) { mx = l[e]; bi = e; }  // first-max
  float p[8]; float se = 0.f;
  #pragma unroll
  for (int e = 0; e < 8; ++e) { p[e] = expf(l[e] - mx); se += p[e]; }
  float z = mx + logf(se);
  top[n] = bi;
  #pragma unroll
  for (int e = 0; e < 8; ++e) atomicAdd(&pacc[e], p[e] / se);
  atomicAdd(&zacc, z * z);
  __syncthreads();
  if (tid < 8) atomicAdd(&psum[tid], pacc[tid]);
  if (tid == 0) atomicAdd(z2, zacc);
}

// single-wave rank scan (matches stable argsort arrival order)
__global__ void route_scan(const int* __restrict__ top, int* __restrict__ rank,
                           int* __restrict__ cnt) {
  int lane = threadIdx.x;
  int c[8] = {0, 0, 0, 0, 0, 0, 0, 0};
  unsigned long long below = (1ull << lane) - 1ull;
  for (int s = 0; s < Ntok / 64; ++s) {
    int n = s * 64 + lane;
    int e = top[n];
    int r = 0;
    #pragma unroll
    for (int q = 0; q < 8; ++q) {
      unsigned long long m = __ballot(e == q);
      if (e == q) r = c[q] + __popcll(m & below);
      c[q] += __popcll(m);
    }
    rank[n] = r;
  }
  #pragma unroll
  for (int q = 0; q < 8; ++q) if (lane == q) cnt[q] = c[q];
}

// ffn f32 -> xb16 split (E*384, 1536=[hi768|lo768])
__global__ void scatter_xb(const float* __restrict__ xin, const int* __restrict__ top,
                           const int* __restrict__ rank, unsigned short* __restrict__ xb) {
  int n = blockIdx.x;
  int r = rank[n];
  if (r >= CAPc) return;
  int e = top[n];
  int t = threadIdx.x;
  if (t >= 192) return;
  float4 v = ((const float4*)(xin + (long long)n * 768))[t];
  ushort4 h, l;
  splitf16(v.x, h.x, l.x); splitf16(v.y, h.y, l.y);
  splitf16(v.z, h.z, l.z); splitf16(v.w, h.w, l.w);
  unsigned short* dst = xb + ((long long)e * CAPPc + r) * 1536 + t * 4;
  *(ushort4*)dst = h;
  *(ushort4*)(dst + 768) = l;
}

// gu f32 (rows,4096=[g2048|u2048]) -> act16 split (rows, 4096=[hi2048|lo2048])
__global__ void __launch_bounds__(256) silu_k(const float* __restrict__ gu,
                                              unsigned short* __restrict__ act) {
  long long i = (long long)blockIdx.x * 256 + threadIdx.x;  // < E*CAPP*H
  long long row = i >> 11;
  int h = (int)(i & 2047);
  float g = gu[row * 4096 + h];
  float u = gu[row * 4096 + 2048 + h];
  float a = g / (1.f + expf(-g)) * u;
  unsigned short hh, ll;
  splitf16(a, hh, ll);
  act[row * 4096 + h] = hh;
  act[row * 4096 + 2048 + h] = ll;
}

__global__ void gather_add(const float* __restrict__ h, const float* __restrict__ yexp,
                           const int* __restrict__ top, const int* __restrict__ rank,
                           float* __restrict__ xo) {
  int n = blockIdx.x;
  int r = rank[n], e = top[n];
  bool kept = r < CAPc;
  int rc = kept ? r : (CAPc - 1);
  const float4* hs = (const float4*)(h + (long long)n * 768);
  const float4* ys = (const float4*)(yexp + ((long long)e * CAPPc + rc) * 768);
  float4* dst = (float4*)(xo + (long long)n * 768);
  int t = threadIdx.x;
  if (t < 192) {
    float4 v = hs[t];
    if (kept) { float4 y = ys[t]; v.x += y.x; v.y += y.y; v.z += y.z; v.w += y.w; }
    dst[t] = v;
  }
}

__global__ void aux_fin(const float* __restrict__ psum, const int* __restrict__ cnt,
                        const float* __restrict__ z2, float* __restrict__ outp) {
  if (threadIdx.x == 0) {
    float aux = 0.f;
    for (int l = 0; l < Lc; ++l) {
      float bl = 0.f;
      for (int e = 0; e < 8; ++e)
        bl += (psum[l * 8 + e] * (1.0f / 2048.0f)) * ((float)cnt[l * 8 + e] * (1.0f / 2048.0f));
      aux += bl * (0.01f * 8.0f) + (z2[l] * (1.0f / 2048.0f)) * 0.001f;
    }
    outp[0] = aux;
  }
}

// ---------------- fp16 MFMA GEMM (global_load_lds staging) ----------------
// C(M,N) f32 [+Add] = A @ Bt^T.  A:(M,lda) fp16, Bt:(N,lda) fp16 pre-transposed.
// SPLIT=1: storage [hi K | lo K] (lda=2K); 3 terms AhBh, AlBh, AhBl.
// CKLIM=1: truncate K to m0+128 (PV causal; P zero beyond diagonal).
// Staging: thread tid writes LDS bytes tid*16 per 64-row stage -> wave-uniform
// base + lane*16 == global_load_lds layout. Global source per-lane (NTAIL clamp ok).
template <int BN, int SPLIT, int ADD, int NTAIL, int CAUSAL, int CKLIM>
__global__ void __launch_bounds__(256) gemm_h(
    const unsigned short* __restrict__ A, const unsigned short* __restrict__ Bt,
    float* __restrict__ C, const float* __restrict__ Add,
    int M, int N, int K, int ldc, int gx, int gy,
    long long sA, long long sB, int zdiv, long long sC1, long long sC2) {
  constexpr int FN = (BN == 128) ? 4 : 2;
  __shared__ __align__(16) unsigned short As[128 * 32];
  __shared__ __align__(16) unsigned short Bs[BN * 32];
  int tot = gridDim.x;
  int lin = blockIdx.x;
  if ((tot & 7) == 0) lin = (lin & 7) * (tot >> 3) + (lin >> 3);  // XCD chunking
  int pz = lin / (gx * gy);
  int r2 = lin - pz * (gx * gy);
  const int m0 = (r2 % gx) * 128, n0 = (r2 / gx) * BN;
  if (CAUSAL && n0 > m0 + 127) return;
  A += (long long)pz * sA;
  Bt += (long long)pz * sB;
  const long long co = (long long)(pz / zdiv) * sC1 + (long long)(pz % zdiv) * sC2;
  const int lda = SPLIT ? 2 * K : K;
  const int Ke = CKLIM ? min(K, m0 + 128) : K;
  const int n1 = Ke / 32;
  const int NS = SPLIT ? 3 * n1 : n1;
  const int tid = threadIdx.x;
  const int lane = tid & 63, wave = tid >> 6;
  const int wm = (BN == 128) ? (wave >> 1) : (wave & 1);
  const int wn = (BN == 128) ? (wave & 1) : (wave >> 1);
  const int srow = tid >> 2, scol = (tid & 3) * 8;
  // per-thread global row base pointers for staging
  const unsigned short* Ar = A + (long long)(m0 + srow) * lda + scol;
  int br0 = n0 + srow;
  if (NTAIL) br0 = min(br0, N - 1);
  const unsigned short* Br = Bt + (long long)br0 * lda + scol;
  int br1 = n0 + srow + 64;
  if (NTAIL) br1 = min(br1, N - 1);
  const unsigned short* Br2 = Bt + (long long)br1 * lda + scol;
  f32x4 acc[4][FN];
  #pragma unroll
  for (int m = 0; m < 4; ++m)
    #pragma unroll
    for (int n = 0; n < FN; ++n) acc[m][n] = (f32x4){0.f, 0.f, 0.f, 0.f};
  for (int s = 0; s < NS; ++s) {
    const int t = (s >= 2 * n1) ? 2 : ((s >= n1) ? 1 : 0);
    const int ks = (s - t * n1) * 32;
    const int kA = (SPLIT && t == 1) ? K + ks : ks;
    const int kB = (SPLIT && t == 2) ? K + ks : ks;
    gload16(Ar + kA, &As[wave * 512]);
    gload16(Ar + (long long)64 * lda + kA, &As[2048 + wave * 512]);
    gload16(Br + kB, &Bs[wave * 512]);
    if (BN == 128) gload16(Br2 + kB, &Bs[2048 + wave * 512]);
    __syncthreads();
    half8 bf[FN];
    #pragma unroll
    for (int n = 0; n < FN; ++n)
      bf[n] = *(const half8*)&Bs[(wn * (FN * 16) + n * 16 + (lane & 15)) * 32 + (lane >> 4) * 8];
    #pragma unroll
    for (int m = 0; m < 4; ++m) {
      half8 af = *(const half8*)&As[(wm * 64 + m * 16 + (lane & 15)) * 32 + (lane >> 4) * 8];
      #pragma unroll
      for (int n = 0; n < FN; ++n)
        acc[m][n] = __builtin_amdgcn_mfma_f32_16x16x32_f16(af, bf[n], acc[m][n], 0, 0, 0);
    }
    __syncthreads();
  }
  #pragma unroll
  for (int m = 0; m < 4; ++m)
    #pragma unroll
    for (int n = 0; n < FN; ++n) {
      int col = n0 + wn * (FN * 16) + n * 16 + (lane & 15);
      if (!NTAIL || col < N) {
        #pragma unroll
        for (int j = 0; j < 4; ++j) {
          long long row = m0 + wm * 64 + m * 16 + (lane >> 4) * 4 + j;
          long long o = co + row * ldc + col;
          float v = acc[m][n][j];
          if (ADD) v += Add[o];
          C[o] = v;
        }
      }
    }
}

// ---------------- host launch ----------------

extern "C" void kernel_launch(void* const* d_in, const int* in_sizes, int n_in,
                              void* d_out, int out_size, void* d_ws, size_t ws_size,
                              hipStream_t stream) {
  (void)in_sizes; (void)n_in; (void)out_size; (void)ws_size;
  const int*   idx   = (const int*)d_in[0];
  const float* wte   = (const float*)d_in[1];
  const float* wqkv  = (const float*)d_in[2];
  const float* qnw   = (const float*)d_in[3];
  const float* knw   = (const float*)d_in[4];
  const float* oproj = (const float*)d_in[5];
  const float* ffnw  = (const float*)d_in[6];
  const float* gatew = (const float*)d_in[7];
  const float* w13   = (const float*)d_in[8];
  const float* w2p   = (const float*)d_in[9];
  const float* lnf   = (const float*)d_in[10];
  float* out = (float*)d_out;

  char* base = (char*)d_ws;
  size_t off = 0;
  auto alloc = [&](size_t bytes) -> char* {
    off = (off + 255) & ~(size_t)255;
    char* p = base + off; off += bytes; return p;
  };
  float* x     = (float*)alloc((size_t)Ntok * 768 * 4);
  float* qkv   = (float*)alloc((size_t)Ntok * 2304 * 4);
  float* hbuf  = (float*)alloc((size_t)Ntok * 768 * 4);
  float* ffn   = (float*)alloc((size_t)Ntok * 768 * 4);
  float* yfl   = (float*)alloc((size_t)Ntok * 768 * 4);
  unsigned short* x16   = (unsigned short*)alloc((size_t)Ntok * 1536 * 2);
  unsigned short* yfl16 = (unsigned short*)alloc((size_t)Ntok * 1536 * 2);
  unsigned short* qr16  = (unsigned short*)alloc((size_t)24 * 1024 * 128 * 2);
  unsigned short* kr16  = (unsigned short*)alloc((size_t)24 * 1024 * 128 * 2);
  unsigned short* vr16  = (unsigned short*)alloc((size_t)24 * 64 * 2048 * 2);
  unsigned short* xb16  = (unsigned short*)alloc((size_t)Ec * CAPPc * 1536 * 2);
  unsigned short* wo16  = (unsigned short*)alloc((size_t)768 * 1536 * 2);
  unsigned short* xf16  = (unsigned short*)alloc((size_t)Ntok * 768 * 2);
  char* spb = alloc((size_t)24 * 1024 * 1024 * 4);          // 100.66 MB scores
  float* sp   = (float*)spb;
  float* gu   = (float*)spb;                                 // alias [0, 50.3M)
  float* yexp = (float*)spb;                                 // alias [0, 9.4M)
  unsigned short* act16 = (unsigned short*)(spb + 50331648); // alias [50.3M, 75.5M)
  unsigned short* wq16  = (unsigned short*)(spb + 75497472); // alias [75.5M, 82.6M)
  unsigned short* w13_16 = (unsigned short*)alloc((size_t)Ec * 4096 * 1536 * 2); // 100.66MB
  unsigned short* wt16   = w13_16;                           // alias (used after)
  unsigned short* w2_16  = (unsigned short*)alloc((size_t)Ec * 768 * 4096 * 2);  // 50.3MB
  int* top    = (int*)alloc(Ntok * 4);
  int* rankb  = (int*)alloc(Ntok * 4);
  int* cnt    = (int*)alloc(Lc * Ec * 4);
  float* psum = (float*)alloc(Lc * Ec * 4);
  float* z2   = (float*)alloc(Lc * 4);

  zero_small<<<1, 64, 0, stream>>>(psum, z2);
  embed_k<<<Ntok, 192, 0, stream>>>(idx, wte, x);

  for (int l = 0; l < Lc; ++l) {
    split2_rows<<<(Ntok * 192 + 255) / 256, 256, 0, stream>>>(x, x16, 768, (long long)Ntok * 192);
    split2_wT<<<dim3(72, 24, 1), 256, 0, stream>>>(wqkv + (size_t)l * 768 * 2304, wq16,
                                                   768, 2304, 0, 0);
    split2_wT<<<dim3(24, 24, 1), 256, 0, stream>>>(oproj + (size_t)l * 768 * 768, wo16,
                                                   768, 768, 0, 0);
    split2_wT<<<dim3(128, 24, 8), 256, 0, stream>>>(w13 + (size_t)l * Ec * 768 * 4096, w13_16,
                                                    768, 4096, (long long)768 * 4096,
                                                    (long long)4096 * 1536);
    split2_wT<<<dim3(24, 64, 8), 256, 0, stream>>>(w2p + (size_t)l * Ec * 2048 * 768, w2_16,
                                                   2048, 768, (long long)2048 * 768,
                                                   (long long)768 * 4096);
    // qkv = x @ wqkv[l]
    gemm_h<128, 1, 0, 0, 0, 0><<<288, 256, 0, stream>>>(
        x16, wq16, qkv, nullptr, 2048, 2304, 768, 2304, 16, 18, 0, 0, 1, 0, 0);
    rmsnorm_k<<<Ntok, 256, 0, stream>>>(qkv,       2304, qkv,       2304, qnw + l * 768);
    rmsnorm_k<<<Ntok, 256, 0, stream>>>(qkv + 768, 2304, qkv + 768, 2304, knw + l * 768);
    rope_split<<<(Ntok * 12 * 32) / 256, 256, 0, stream>>>(qkv, qr16, kr16, vr16);
    // scores = q @ k^T per (b,h), causal tile skip
    gemm_h<128, 1, 0, 0, 1, 0><<<1536, 256, 0, stream>>>(
        qr16, kr16, sp, nullptr, 1024, 1024, 64, 1024, 8, 8,
        (long long)1024 * 128, (long long)1024 * 128, 1, (long long)1024 * 1024, 0);
    softmax_causal<<<dim3(1024, 24), 256, 0, stream>>>(sp);
    // y = P @ V with causal K-truncation (P = sp reinterpreted as split-fp16)
    gemm_h<64, 1, 0, 0, 0, 1><<<192, 256, 0, stream>>>(
        (const unsigned short*)sp, vr16, yfl, nullptr, 1024, 64, 1024, 768, 8, 1,
        (long long)1024 * 2048, (long long)64 * 2048, 12, (long long)1024 * 768, 64);
    split2_rows<<<(Ntok * 192 + 255) / 256, 256, 0, stream>>>(yfl, yfl16, 768,
                                                              (long long)Ntok * 192);
    // h = x + y @ o_proj[l]
    gemm_h<128, 1, 1, 0, 0, 0><<<96, 256, 0, stream>>>(
        yfl16, wo16, hbuf, x, 2048, 768, 768, 768, 16, 6, 0, 0, 1, 0, 0);
    rmsnorm_k<<<Ntok, 256, 0, stream>>>(hbuf, 768, ffn, 768, ffnw + l * 768);
    gate_k<<<Ntok / 256, 256, 0, stream>>>(ffn, gatew + (size_t)l * 768 * 8, top,
                                           psum + l * 8, z2 + l);
    route_scan<<<1, 64, 0, stream>>>(top, rankb, cnt + l * 8);
    scatter_xb<<<Ntok, 192, 0, stream>>>(ffn, top, rankb, xb16);
    // gu = xb @ w13[l]  (batched over experts)
    gemm_h<128, 1, 0, 0, 0, 0><<<768, 256, 0, stream>>>(
        xb16, w13_16, gu, nullptr, 384, 4096, 768, 4096, 3, 32,
        (long long)384 * 1536, (long long)4096 * 1536, 1, (long long)384 * 4096, 0);
    silu_k<<<(Ec * CAPPc * Hc) / 256, 256, 0, stream>>>(gu, act16);
    // yexp = act @ w2[l]
    gemm_h<64, 1, 0, 0, 0, 0><<<288, 256, 0, stream>>>(
        act16, w2_16, yexp, nullptr, 384, 768, 2048, 768, 3, 12,
        (long long)384 * 4096, (long long)768 * 4096, 1, (long long)384 * 768, 0);
    gather_add<<<Ntok, 192, 0, stream>>>(hbuf, yexp, top, rankb, x);
  }

  rmsnorm_h<<<Ntok, 256, 0, stream>>>(x, xf16, lnf);
  f2h4<<<(int)(((long long)Vc * 768 / 4 + 255) / 256), 256, 0, stream>>>(
      wte, wt16, (long long)Vc * 768 / 4);
  // logits = xf @ wte^T  (single fp16, N tail handled)
  gemm_h<128, 0, 0, 1, 0, 0><<<6288, 256, 0, stream>>>(
      xf16, wt16, out, nullptr, 2048, Vc, 768, Vc, 16, 393, 0, 0, 1, 0, 0);
  aux_fin<<<1, 64, 0, stream>>>(psum, cnt, z2, out + LOGITS_N);
}

// Round 4
// 1584.410 us; speedup vs baseline: 1.0850x; 1.0850x over previous
//
// LunarisCodex MoE-GPT forward, MI355X/gfx950. Round 4: fused flash attention
// (QK^T -> online softmax -> PV in one kernel), layer-1 experts in single fp16
// (post-gate), conversion passes fused into producers.
// Precision: split-fp16 x3 upstream of gates (routing-exact); fp16 logits GEMM.
#include <hip/hip_runtime.h>

typedef __attribute__((ext_vector_type(8))) _Float16 half8;
typedef __attribute__((ext_vector_type(4))) float f32x4;

constexpr int Bc = 2, Tc = 1024, Dc = 768, NHc = 12, HDc = 64;
constexpr int Vc = 50257, Lc = 2, Ec = 8, Hc = 2048;
constexpr int Ntok = Bc * Tc;            // 2048
constexpr int CAPc = 320, CAPPc = 384;   // capacity, padded rows per expert
constexpr long long LOGITS_N = (long long)Bc * Tc * Vc;  // 102926336

typedef const __attribute__((address_space(1))) unsigned int* gas_t;
typedef __attribute__((address_space(3))) unsigned int* las_t;
__device__ __forceinline__ void gload16(const void* g, void* l) {
  __builtin_amdgcn_global_load_lds((gas_t)g, (las_t)l, 16, 0, 0);
}

__device__ __forceinline__ void splitf16(float a, unsigned short& h, unsigned short& l) {
  _Float16 hh = (_Float16)a;                       // RNE
  _Float16 ll = (_Float16)(a - (float)hh);
  h = __builtin_bit_cast(unsigned short, hh);
  l = __builtin_bit_cast(unsigned short, ll);
}
__device__ __forceinline__ unsigned short f16o(float a) {
  _Float16 hh = (_Float16)a;
  return __builtin_bit_cast(unsigned short, hh);
}

// ---------------- small kernels ----------------

__global__ void zero_small(float* psum, float* z2) {
  int t = threadIdx.x;
  if (t < Lc * Ec) psum[t] = 0.f;
  if (t < Lc) z2[t] = 0.f;
}

// embed: x (f32) + x16 (split-fp16 [hi768|lo768])
__global__ void embed_k(const int* __restrict__ idx, const float* __restrict__ wte,
                        float* __restrict__ x, unsigned short* __restrict__ x16) {
  int n = blockIdx.x;
  long long v = idx[n];
  const float4* src = (const float4*)(wte + v * 768);
  float4* dst = (float4*)(x + (long long)n * 768);
  int t = threadIdx.x;
  if (t < 192) {
    float4 val = src[t];
    dst[t] = val;
    ushort4 h, l;
    splitf16(val.x, h.x, l.x); splitf16(val.y, h.y, l.y);
    splitf16(val.z, h.z, l.z); splitf16(val.w, h.w, l.w);
    unsigned short* d = x16 + (long long)n * 1536 + t * 4;
    *(ushort4*)d = h;
    *(ushort4*)(d + 768) = l;
  }
}

// f32 -> fp16 single (for wte)
__global__ void f2h4(const float* __restrict__ in, unsigned short* __restrict__ out,
                     long long n4) {
  long long i = (long long)blockIdx.x * 256 + threadIdx.x;
  if (i >= n4) return;
  float4 v = ((const float4*)in)[i];
  ushort4 o;
  o.x = f16o(v.x); o.y = f16o(v.y); o.z = f16o(v.z); o.w = f16o(v.w);
  ((ushort4*)out)[i] = o;
}

// f32 weights (K,N) -> fp16 transposed. SP=1: (N,2K) [hi|lo]; SP=0: (N,K) hi only.
template <int SP>
__global__ void __launch_bounds__(256) split2_wT(const float* __restrict__ src,
    unsigned short* __restrict__ dst, int K, int N, long long sS, long long sD) {
  __shared__ float t[32][33];
  int z = blockIdx.z;
  src += (long long)z * sS;
  dst += (long long)z * sD;
  int n0 = blockIdx.x * 32, k0 = blockIdx.y * 32;
  int tid = threadIdx.x;
  int r = tid >> 3, c4 = (tid & 7) * 4;
  float4 v = *(const float4*)(src + (long long)(k0 + r) * N + n0 + c4);
  t[r][c4 + 0] = v.x; t[r][c4 + 1] = v.y; t[r][c4 + 2] = v.z; t[r][c4 + 3] = v.w;
  __syncthreads();
  int n = tid >> 3, kq = (tid & 7) * 4;
  ushort4 h, l;
  splitf16(t[kq + 0][n], h.x, l.x);
  splitf16(t[kq + 1][n], h.y, l.y);
  splitf16(t[kq + 2][n], h.z, l.z);
  splitf16(t[kq + 3][n], h.w, l.w);
  const int lda = SP ? 2 * K : K;
  unsigned short* d = dst + (long long)(n0 + n) * lda + k0 + kq;
  *(ushort4*)d = h;
  if (SP) *(ushort4*)(d + K) = l;
}

// rmsnorm over 768 cols; strided in/out, f32 out
__global__ void __launch_bounds__(256) rmsnorm_k(const float* in, int istride,
                                                 float* outp, int ostride,
                                                 const float* w) {
  long long n = blockIdx.x;
  const float* xr = in + n * istride;
  float* yr = outp + n * ostride;
  int tid = threadIdx.x;
  float s = 0.f;
  for (int i = tid; i < 768; i += 256) { float v = xr[i]; s += v * v; }
  #pragma unroll
  for (int o = 32; o; o >>= 1) s += __shfl_down(s, o);
  __shared__ float red[4];
  __shared__ float bs;
  if ((tid & 63) == 0) red[tid >> 6] = s;
  __syncthreads();
  if (tid == 0) bs = rsqrtf((red[0] + red[1] + red[2] + red[3]) / 768.0f + 1e-5f);
  __syncthreads();
  float sc = bs;
  for (int i = tid; i < 768; i += 256) yr[i] = xr[i] * sc * w[i];
}

// rmsnorm -> fp16 single output (final ln before logits)
__global__ void __launch_bounds__(256) rmsnorm_h(const float* in,
                                                 unsigned short* outp, const float* w) {
  long long n = blockIdx.x;
  const float* xr = in + n * 768;
  unsigned short* yr = outp + n * 768;
  int tid = threadIdx.x;
  float s = 0.f;
  for (int i = tid; i < 768; i += 256) { float v = xr[i]; s += v * v; }
  #pragma unroll
  for (int o = 32; o; o >>= 1) s += __shfl_down(s, o);
  __shared__ float red[4];
  __shared__ float bs;
  if ((tid & 63) == 0) red[tid >> 6] = s;
  __syncthreads();
  if (tid == 0) bs = rsqrtf((red[0] + red[1] + red[2] + red[3]) / 768.0f + 1e-5f);
  __syncthreads();
  float sc = bs;
  for (int i = tid; i < 768; i += 256) yr[i] = f16o(xr[i] * sc * w[i]);
}

// qkv (N,2304) f32 -> split-fp16 qr,kr (z,1024,128=[hi64|lo64]) with RoPE,
// and V transposed vr (z,64,2048=[hi 1024 | lo 1024])
__global__ void __launch_bounds__(256) rope_split(const float* __restrict__ qkv,
    unsigned short* __restrict__ qr, unsigned short* __restrict__ kr,
    unsigned short* __restrict__ vr) {
  int i = blockIdx.x * 256 + threadIdx.x;   // < Ntok*12*32
  int j = i & 31;
  int hh = (i >> 5) % 12;
  int n = i / (32 * 12);
  int t = n & 1023;
  float fr = powf(10000.0f, -((float)(2 * j) * (1.0f / 64.0f)));
  float ang = (float)t * fr;
  float c = cosf(ang), s = sinf(ang);
  const float* bp = qkv + (long long)n * 2304 + hh * 64 + 2 * j;
  int z = (n >> 10) * 12 + hh;
  long long qb = ((long long)z * 1024 + t) * 128 + 2 * j;
  unsigned short h0, l0, h1, l1;
  float q0 = bp[0], q1 = bp[1];
  splitf16(q0 * c - q1 * s, h0, l0);
  splitf16(q0 * s + q1 * c, h1, l1);
  *(unsigned int*)&qr[qb] = (unsigned)h0 | ((unsigned)h1 << 16);
  *(unsigned int*)&qr[qb + 64] = (unsigned)l0 | ((unsigned)l1 << 16);
  float k0 = bp[768], k1 = bp[769];
  splitf16(k0 * c - k1 * s, h0, l0);
  splitf16(k0 * s + k1 * c, h1, l1);
  *(unsigned int*)&kr[qb] = (unsigned)h0 | ((unsigned)h1 << 16);
  *(unsigned int*)&kr[qb + 64] = (unsigned)l0 | ((unsigned)l1 << 16);
  float v0 = bp[1536], v1 = bp[1537];
  splitf16(v0, h0, l0);
  splitf16(v1, h1, l1);
  long long vb = ((long long)z * 64 + 2 * j) * 2048 + t;
  vr[vb] = h0; vr[vb + 1024] = l0;
  vr[vb + 2048] = h1; vr[vb + 3072] = l1;
}

// ---------------- fused flash attention ----------------
// Block = (z, q-tile of 64). 4 waves x 16 q-rows. Causal, scale 1/8.
// QK^T and PV via split-fp16 x3 MFMA; online softmax in f32 (wave-local).
// Output written directly as split-fp16 into yfl16 (row n, col h*64+d | +768).
__global__ void __launch_bounds__(256) flash_attn(
    const unsigned short* __restrict__ qr, const unsigned short* __restrict__ kr,
    const unsigned short* __restrict__ vr, unsigned short* __restrict__ yout) {
  __shared__ __align__(16) unsigned short Ph[4][16][72];
  __shared__ __align__(16) unsigned short Pl[4][16][72];
  int bid = blockIdx.x;
  int z = bid >> 4;
  int qt = 15 - (bid & 15);          // heavy tiles first (load balance)
  int b = z / 12, h = z % 12;
  int q0 = qt * 64;
  int wave = threadIdx.x >> 6, lane = threadIdx.x & 63;
  int lr = lane & 15, lg = lane >> 4;
  int qw = q0 + wave * 16;           // this wave's 16 q rows
  // resident Q fragments: [ks(hd32)][hi/lo]
  half8 af[2][2];
  const unsigned short* qbase = qr + ((long long)z * 1024 + qw + lr) * 128;
  #pragma unroll
  for (int ks = 0; ks < 2; ++ks)
    #pragma unroll
    for (int p = 0; p < 2; ++p)
      af[ks][p] = *(const half8*)(qbase + p * 64 + ks * 32 + lg * 8);
  f32x4 accy[4];                     // y: col d=16df+lr, rows lg*4+j
  #pragma unroll
  for (int df = 0; df < 4; ++df) accy[df] = (f32x4){0.f, 0.f, 0.f, 0.f};
  float mrun[4] = {-3.4e38f, -3.4e38f, -3.4e38f, -3.4e38f};
  float srun[4] = {0.f, 0.f, 0.f, 0.f};
  for (int kt = 0; kt <= qt; ++kt) {
    int kv0 = kt * 64;
    // S = Q K^T (rows=q via lg*4+j, cols=kv via 16nf+lr)
    f32x4 s[4];
    #pragma unroll
    for (int nf = 0; nf < 4; ++nf) s[nf] = (f32x4){0.f, 0.f, 0.f, 0.f};
    const unsigned short* kbase = kr + ((long long)z * 1024 + kv0 + lr) * 128;
    #pragma unroll
    for (int nf = 0; nf < 4; ++nf) {
      const unsigned short* kb = kbase + nf * 16 * 128;
      #pragma unroll
      for (int ks = 0; ks < 2; ++ks) {
        half8 bh = *(const half8*)(kb + ks * 32 + lg * 8);
        half8 bl = *(const half8*)(kb + 64 + ks * 32 + lg * 8);
        s[nf] = __builtin_amdgcn_mfma_f32_16x16x32_f16(af[ks][0], bh, s[nf], 0, 0, 0);
        s[nf] = __builtin_amdgcn_mfma_f32_16x16x32_f16(af[ks][1], bh, s[nf], 0, 0, 0);
        s[nf] = __builtin_amdgcn_mfma_f32_16x16x32_f16(af[ks][0], bl, s[nf], 0, 0, 0);
      }
    }
    // scale + causal mask (only diagonal tile can mask)
    bool diag = (kt == qt);
    #pragma unroll
    for (int nf = 0; nf < 4; ++nf)
      #pragma unroll
      for (int j = 0; j < 4; ++j) {
        float v = s[nf][j] * 0.125f;
        if (diag && (nf * 16 + lr > wave * 16 + lg * 4 + j)) v = -1e30f;
        s[nf][j] = v;
      }
    // online softmax per q-row j (16-lane groups hold the 64 cols)
    #pragma unroll
    for (int j = 0; j < 4; ++j) {
      float tm = fmaxf(fmaxf(s[0][j], s[1][j]), fmaxf(s[2][j], s[3][j]));
      #pragma unroll
      for (int o = 1; o < 16; o <<= 1) tm = fmaxf(tm, __shfl_xor(tm, o));
      float mnew = fmaxf(mrun[j], tm);
      float sc = expf(mrun[j] - mnew);
      float ts = 0.f;
      #pragma unroll
      for (int nf = 0; nf < 4; ++nf) {
        float p = expf(s[nf][j] - mnew);
        ts += p;
        unsigned short ph, pl;
        splitf16(p, ph, pl);
        Ph[wave][lg * 4 + j][nf * 16 + lr] = ph;
        Pl[wave][lg * 4 + j][nf * 16 + lr] = pl;
      }
      #pragma unroll
      for (int o = 1; o < 16; o <<= 1) ts += __shfl_xor(ts, o);
      srun[j] = srun[j] * sc + ts;
      mrun[j] = mnew;
      #pragma unroll
      for (int df = 0; df < 4; ++df) accy[df][j] *= sc;
    }
    // PV: A = P (rows=q=lr), B = V^T (rows=d)
    #pragma unroll
    for (int ks2 = 0; ks2 < 2; ++ks2) {
      half8 aph = *(const half8*)&Ph[wave][lr][ks2 * 32 + lg * 8];
      half8 apl = *(const half8*)&Pl[wave][lr][ks2 * 32 + lg * 8];
      #pragma unroll
      for (int df = 0; df < 4; ++df) {
        const unsigned short* vb =
            vr + ((long long)z * 64 + df * 16 + lr) * 2048 + kv0 + ks2 * 32 + lg * 8;
        half8 bvh = *(const half8*)vb;
        half8 bvl = *(const half8*)(vb + 1024);
        accy[df] = __builtin_amdgcn_mfma_f32_16x16x32_f16(aph, bvh, accy[df], 0, 0, 0);
        accy[df] = __builtin_amdgcn_mfma_f32_16x16x32_f16(apl, bvh, accy[df], 0, 0, 0);
        accy[df] = __builtin_amdgcn_mfma_f32_16x16x32_f16(aph, bvl, accy[df], 0, 0, 0);
      }
    }
  }
  // epilogue: divide by denom, write split-fp16 into yfl16
  float inv[4];
  #pragma unroll
  for (int j = 0; j < 4; ++j) inv[j] = 1.0f / srun[j];
  #pragma unroll
  for (int df = 0; df < 4; ++df)
    #pragma unroll
    for (int j = 0; j < 4; ++j) {
      long long tok = (long long)b * 1024 + qw + lg * 4 + j;
      int col = h * 64 + df * 16 + lr;
      unsigned short hh, ll;
      splitf16(accy[df][j] * inv[j], hh, ll);
      yout[tok * 1536 + col] = hh;
      yout[tok * 1536 + 768 + col] = ll;
    }
}

// gate: logits(f32), softmax probs, argmax (first-max), aux accumulators
__global__ void __launch_bounds__(256) gate_k(const float* __restrict__ xin,
    const float* __restrict__ gw, int* __restrict__ top,
    float* __restrict__ psum, float* __restrict__ z2) {
  __shared__ float gws[768 * 8];
  __shared__ float pacc[8];
  __shared__ float zacc;
  int tid = threadIdx.x;
  for (int i = tid; i < 768 * 8 / 4; i += 256) ((float4*)gws)[i] = ((const float4*)gw)[i];
  if (tid < 8) pacc[tid] = 0.f;
  if (tid == 0) zacc = 0.f;
  __syncthreads();
  int n = blockIdx.x * 256 + tid;
  const float4* xr4 = (const float4*)(xin + (long long)n * 768);
  float l[8] = {0, 0, 0, 0, 0, 0, 0, 0};
  for (int d4 = 0; d4 < 192; ++d4) {
    float4 xv = xr4[d4];
    const float* g = &gws[d4 * 32];
    #pragma unroll
    for (int e = 0; e < 8; ++e)
      l[e] += xv.x * g[e] + xv.y * g[8 + e] + xv.z * g[16 + e] + xv.w * g[24 + e];
  }
  float mx = l[0]; int bi = 0;
  #pragma unroll
  for (int e = 1; e < 8; ++e) if (l[e] > mx) { mx = l[e]; bi = e; }  // first-max
  float p[8]; float se = 0.f;
  #pragma unroll
  for (int e = 0; e < 8; ++e) { p[e] = expf(l[e] - mx); se += p[e]; }
  float z = mx + logf(se);
  top[n] = bi;
  #pragma unroll
  for (int e = 0; e < 8; ++e) atomicAdd(&pacc[e], p[e] / se);
  atomicAdd(&zacc, z * z);
  __syncthreads();
  if (tid < 8) atomicAdd(&psum[tid], pacc[tid]);
  if (tid == 0) atomicAdd(z2, zacc);
}

// single-wave rank scan (matches stable argsort arrival order)
__global__ void route_scan(const int* __restrict__ top, int* __restrict__ rank,
                           int* __restrict__ cnt) {
  int lane = threadIdx.x;
  int c[8] = {0, 0, 0, 0, 0, 0, 0, 0};
  unsigned long long below = (1ull << lane) - 1ull;
  for (int s = 0; s < Ntok / 64; ++s) {
    int n = s * 64 + lane;
    int e = top[n];
    int r = 0;
    #pragma unroll
    for (int q = 0; q < 8; ++q) {
      unsigned long long m = __ballot(e == q);
      if (e == q) r = c[q] + __popcll(m & below);
      c[q] += __popcll(m);
    }
    rank[n] = r;
  }
  #pragma unroll
  for (int q = 0; q < 8; ++q) if (lane == q) cnt[q] = c[q];
}

// ffn f32 -> xb16. SP=1: (row,1536=[hi|lo]); SP=0: (row,768) hi only.
template <int SP>
__global__ void scatter_xb(const float* __restrict__ xin, const int* __restrict__ top,
                           const int* __restrict__ rank, unsigned short* __restrict__ xb) {
  int n = blockIdx.x;
  int r = rank[n];
  if (r >= CAPc) return;
  int e = top[n];
  int t = threadIdx.x;
  if (t >= 192) return;
  float4 v = ((const float4*)(xin + (long long)n * 768))[t];
  ushort4 h, l;
  splitf16(v.x, h.x, l.x); splitf16(v.y, h.y, l.y);
  splitf16(v.z, h.z, l.z); splitf16(v.w, h.w, l.w);
  const int lda = SP ? 1536 : 768;
  unsigned short* dst = xb + ((long long)e * CAPPc + r) * lda + t * 4;
  *(ushort4*)dst = h;
  if (SP) *(ushort4*)(dst + 768) = l;
}

// gu f32 (rows,4096=[g|u]) -> act16. SP=1: (rows,4096=[hi2048|lo2048]); SP=0: (rows,2048).
template <int SP>
__global__ void __launch_bounds__(256) silu_k(const float* __restrict__ gu,
                                              unsigned short* __restrict__ act) {
  long long i = (long long)blockIdx.x * 256 + threadIdx.x;  // < E*CAPP*H
  long long row = i >> 11;
  int h = (int)(i & 2047);
  float g = gu[row * 4096 + h];
  float u = gu[row * 4096 + 2048 + h];
  float a = g / (1.f + expf(-g)) * u;
  if (SP) {
    unsigned short hh, ll;
    splitf16(a, hh, ll);
    act[row * 4096 + h] = hh;
    act[row * 4096 + 2048 + h] = ll;
  } else {
    act[row * 2048 + h] = f16o(a);
  }
}

// h + expert-out -> x (f32) AND x16 (split-fp16) for next layer
__global__ void gather_add(const float* __restrict__ h, const float* __restrict__ yexp,
                           const int* __restrict__ top, const int* __restrict__ rank,
                           float* __restrict__ xo, unsigned short* __restrict__ x16) {
  int n = blockIdx.x;
  int r = rank[n], e = top[n];
  bool kept = r < CAPc;
  int rc = kept ? r : (CAPc - 1);
  const float4* hs = (const float4*)(h + (long long)n * 768);
  const float4* ys = (const float4*)(yexp + ((long long)e * CAPPc + rc) * 768);
  float4* dst = (float4*)(xo + (long long)n * 768);
  int t = threadIdx.x;
  if (t < 192) {
    float4 v = hs[t];
    if (kept) { float4 y = ys[t]; v.x += y.x; v.y += y.y; v.z += y.z; v.w += y.w; }
    dst[t] = v;
    ushort4 hh, ll;
    splitf16(v.x, hh.x, ll.x); splitf16(v.y, hh.y, ll.y);
    splitf16(v.z, hh.z, ll.z); splitf16(v.w, hh.w, ll.w);
    unsigned short* d = x16 + (long long)n * 1536 + t * 4;
    *(ushort4*)d = hh;
    *(ushort4*)(d + 768) = ll;
  }
}

__global__ void aux_fin(const float* __restrict__ psum, const int* __restrict__ cnt,
                        const float* __restrict__ z2, float* __restrict__ outp) {
  if (threadIdx.x == 0) {
    float aux = 0.f;
    for (int l = 0; l < Lc; ++l) {
      float bl = 0.f;
      for (int e = 0; e < 8; ++e)
        bl += (psum[l * 8 + e] * (1.0f / 2048.0f)) * ((float)cnt[l * 8 + e] * (1.0f / 2048.0f));
      aux += bl * (0.01f * 8.0f) + (z2[l] * (1.0f / 2048.0f)) * 0.001f;
    }
    outp[0] = aux;
  }
}

// ---------------- fp16 MFMA GEMM (global_load_lds staging) ----------------
// C(M,N) f32 [+Add] = A @ Bt^T.  A:(M,lda) fp16, Bt:(N,lda) fp16 pre-transposed.
// SPLIT=1: [hi K|lo K] (lda=2K), 3 terms. SPLIT=0: plain fp16 (lda=K).
template <int BN, int SPLIT, int ADD, int NTAIL>
__global__ void __launch_bounds__(256) gemm_h(
    const unsigned short* __restrict__ A, const unsigned short* __restrict__ Bt,
    float* __restrict__ C, const float* __restrict__ Add,
    int M, int N, int K, int ldc, int gx, int gy,
    long long sA, long long sB, int zdiv, long long sC1, long long sC2) {
  constexpr int FN = (BN == 128) ? 4 : 2;
  __shared__ __align__(16) unsigned short As[128 * 32];
  __shared__ __align__(16) unsigned short Bs[BN * 32];
  int tot = gridDim.x;
  int lin = blockIdx.x;
  if ((tot & 7) == 0) lin = (lin & 7) * (tot >> 3) + (lin >> 3);  // XCD chunking
  int pz = lin / (gx * gy);
  int r2 = lin - pz * (gx * gy);
  const int m0 = (r2 % gx) * 128, n0 = (r2 / gx) * BN;
  A += (long long)pz * sA;
  Bt += (long long)pz * sB;
  const long long co = (long long)(pz / zdiv) * sC1 + (long long)(pz % zdiv) * sC2;
  const int lda = SPLIT ? 2 * K : K;
  const int n1 = K / 32;
  const int NS = SPLIT ? 3 * n1 : n1;
  const int tid = threadIdx.x;
  const int lane = tid & 63, wave = tid >> 6;
  const int wm = (BN == 128) ? (wave >> 1) : (wave & 1);
  const int wn = (BN == 128) ? (wave & 1) : (wave >> 1);
  const int srow = tid >> 2, scol = (tid & 3) * 8;
  const unsigned short* Ar = A + (long long)(m0 + srow) * lda + scol;
  int br0 = n0 + srow;
  if (NTAIL) br0 = min(br0, N - 1);
  const unsigned short* Br = Bt + (long long)br0 * lda + scol;
  int br1 = n0 + srow + 64;
  if (NTAIL) br1 = min(br1, N - 1);
  const unsigned short* Br2 = Bt + (long long)br1 * lda + scol;
  f32x4 acc[4][FN];
  #pragma unroll
  for (int m = 0; m < 4; ++m)
    #pragma unroll
    for (int n = 0; n < FN; ++n) acc[m][n] = (f32x4){0.f, 0.f, 0.f, 0.f};
  for (int s = 0; s < NS; ++s) {
    const int t = (s >= 2 * n1) ? 2 : ((s >= n1) ? 1 : 0);
    const int ks = (s - t * n1) * 32;
    const int kA = (SPLIT && t == 1) ? K + ks : ks;
    const int kB = (SPLIT && t == 2) ? K + ks : ks;
    gload16(Ar + kA, &As[wave * 512]);
    gload16(Ar + (long long)64 * lda + kA, &As[2048 + wave * 512]);
    gload16(Br + kB, &Bs[wave * 512]);
    if (BN == 128) gload16(Br2 + kB, &Bs[2048 + wave * 512]);
    __syncthreads();
    half8 bf[FN];
    #pragma unroll
    for (int n = 0; n < FN; ++n)
      bf[n] = *(const half8*)&Bs[(wn * (FN * 16) + n * 16 + (lane & 15)) * 32 + (lane >> 4) * 8];
    #pragma unroll
    for (int m = 0; m < 4; ++m) {
      half8 afm = *(const half8*)&As[(wm * 64 + m * 16 + (lane & 15)) * 32 + (lane >> 4) * 8];
      #pragma unroll
      for (int n = 0; n < FN; ++n)
        acc[m][n] = __builtin_amdgcn_mfma_f32_16x16x32_f16(afm, bf[n], acc[m][n], 0, 0, 0);
    }
    __syncthreads();
  }
  #pragma unroll
  for (int m = 0; m < 4; ++m)
    #pragma unroll
    for (int n = 0; n < FN; ++n) {
      int col = n0 + wn * (FN * 16) + n * 16 + (lane & 15);
      if (!NTAIL || col < N) {
        #pragma unroll
        for (int j = 0; j < 4; ++j) {
          long long row = m0 + wm * 64 + m * 16 + (lane >> 4) * 4 + j;
          long long o = co + row * ldc + col;
          float v = acc[m][n][j];
          if (ADD) v += Add[o];
          C[o] = v;
        }
      }
    }
}

// ---------------- host launch ----------------

extern "C" void kernel_launch(void* const* d_in, const int* in_sizes, int n_in,
                              void* d_out, int out_size, void* d_ws, size_t ws_size,
                              hipStream_t stream) {
  (void)in_sizes; (void)n_in; (void)out_size; (void)ws_size;
  const int*   idx   = (const int*)d_in[0];
  const float* wte   = (const float*)d_in[1];
  const float* wqkv  = (const float*)d_in[2];
  const float* qnw   = (const float*)d_in[3];
  const float* knw   = (const float*)d_in[4];
  const float* oproj = (const float*)d_in[5];
  const float* ffnw  = (const float*)d_in[6];
  const float* gatew = (const float*)d_in[7];
  const float* w13   = (const float*)d_in[8];
  const float* w2p   = (const float*)d_in[9];
  const float* lnf   = (const float*)d_in[10];
  float* out = (float*)d_out;

  char* base = (char*)d_ws;
  size_t off = 0;
  auto alloc = [&](size_t bytes) -> char* {
    off = (off + 255) & ~(size_t)255;
    char* p = base + off; off += bytes; return p;
  };
  float* x     = (float*)alloc((size_t)Ntok * 768 * 4);
  float* qkv   = (float*)alloc((size_t)Ntok * 2304 * 4);
  float* hbuf  = (float*)alloc((size_t)Ntok * 768 * 4);
  float* ffn   = (float*)alloc((size_t)Ntok * 768 * 4);
  unsigned short* x16   = (unsigned short*)alloc((size_t)Ntok * 1536 * 2);
  unsigned short* yfl16 = (unsigned short*)alloc((size_t)Ntok * 1536 * 2);
  unsigned short* qr16  = (unsigned short*)alloc((size_t)24 * 1024 * 128 * 2);
  unsigned short* kr16  = (unsigned short*)alloc((size_t)24 * 1024 * 128 * 2);
  unsigned short* vr16  = (unsigned short*)alloc((size_t)24 * 64 * 2048 * 2);
  unsigned short* xb16  = (unsigned short*)alloc((size_t)Ec * CAPPc * 1536 * 2);
  unsigned short* wo16  = (unsigned short*)alloc((size_t)768 * 1536 * 2);
  unsigned short* xf16  = (unsigned short*)alloc((size_t)Ntok * 768 * 2);
  char* spb = alloc((size_t)24 * 1024 * 1024 * 4);           // scratch region
  float* gu   = (float*)spb;                                 // [0, 50.3M)
  float* yexp = (float*)spb;                                 // [0, 9.4M) over dead gu
  unsigned short* act16 = (unsigned short*)(spb + 50331648); // [50.3M, 75.5M)
  unsigned short* wq16  = (unsigned short*)(spb + 75497472); // [75.5M, 82.6M)
  unsigned short* w13_16 = (unsigned short*)alloc((size_t)Ec * 4096 * 1536 * 2); // 100.66MB
  unsigned short* wt16   = w13_16;                           // alias (used after)
  unsigned short* w2_16  = (unsigned short*)alloc((size_t)Ec * 768 * 4096 * 2);  // 50.3MB
  int* top    = (int*)alloc(Ntok * 4);
  int* rankb  = (int*)alloc(Ntok * 4);
  int* cnt    = (int*)alloc(Lc * Ec * 4);
  float* psum = (float*)alloc(Lc * Ec * 4);
  float* z2   = (float*)alloc(Lc * 4);

  zero_small<<<1, 64, 0, stream>>>(psum, z2);
  embed_k<<<Ntok, 192, 0, stream>>>(idx, wte, x, x16);

  for (int l = 0; l < Lc; ++l) {
    split2_wT<1><<<dim3(72, 24, 1), 256, 0, stream>>>(wqkv + (size_t)l * 768 * 2304, wq16,
                                                      768, 2304, 0, 0);
    split2_wT<1><<<dim3(24, 24, 1), 256, 0, stream>>>(oproj + (size_t)l * 768 * 768, wo16,
                                                      768, 768, 0, 0);
    if (l == 0) {
      split2_wT<1><<<dim3(128, 24, 8), 256, 0, stream>>>(w13, w13_16,
          768, 4096, (long long)768 * 4096, (long long)4096 * 1536);
      split2_wT<1><<<dim3(24, 64, 8), 256, 0, stream>>>(w2p, w2_16,
          2048, 768, (long long)2048 * 768, (long long)768 * 4096);
    } else {
      split2_wT<0><<<dim3(128, 24, 8), 256, 0, stream>>>(w13 + (size_t)Ec * 768 * 4096, w13_16,
          768, 4096, (long long)768 * 4096, (long long)4096 * 768);
      split2_wT<0><<<dim3(24, 64, 8), 256, 0, stream>>>(w2p + (size_t)Ec * 2048 * 768, w2_16,
          2048, 768, (long long)2048 * 768, (long long)768 * 2048);
    }
    // qkv = x @ wqkv[l]
    gemm_h<128, 1, 0, 0><<<288, 256, 0, stream>>>(
        x16, wq16, qkv, nullptr, 2048, 2304, 768, 2304, 16, 18, 0, 0, 1, 0, 0);
    rmsnorm_k<<<Ntok, 256, 0, stream>>>(qkv,       2304, qkv,       2304, qnw + l * 768);
    rmsnorm_k<<<Ntok, 256, 0, stream>>>(qkv + 768, 2304, qkv + 768, 2304, knw + l * 768);
    rope_split<<<(Ntok * 12 * 32) / 256, 256, 0, stream>>>(qkv, qr16, kr16, vr16);
    // fused attention -> yfl16 (split-fp16)
    flash_attn<<<384, 256, 0, stream>>>(qr16, kr16, vr16, yfl16);
    // h = x + y @ o_proj[l]
    gemm_h<128, 1, 1, 0><<<96, 256, 0, stream>>>(
        yfl16, wo16, hbuf, x, 2048, 768, 768, 768, 16, 6, 0, 0, 1, 0, 0);
    rmsnorm_k<<<Ntok, 256, 0, stream>>>(hbuf, 768, ffn, 768, ffnw + l * 768);
    gate_k<<<Ntok / 256, 256, 0, stream>>>(ffn, gatew + (size_t)l * 768 * 8, top,
                                           psum + l * 8, z2 + l);
    route_scan<<<1, 64, 0, stream>>>(top, rankb, cnt + l * 8);
    if (l == 0) {
      scatter_xb<1><<<Ntok, 192, 0, stream>>>(ffn, top, rankb, xb16);
      gemm_h<128, 1, 0, 0><<<768, 256, 0, stream>>>(
          xb16, w13_16, gu, nullptr, 384, 4096, 768, 4096, 3, 32,
          (long long)384 * 1536, (long long)4096 * 1536, 1, (long long)384 * 4096, 0);
      silu_k<1><<<(Ec * CAPPc * Hc) / 256, 256, 0, stream>>>(gu, act16);
      gemm_h<64, 1, 0, 0><<<288, 256, 0, stream>>>(
          act16, w2_16, yexp, nullptr, 384, 768, 2048, 768, 3, 12,
          (long long)384 * 4096, (long long)768 * 4096, 1, (long long)384 * 768, 0);
    } else {
      scatter_xb<0><<<Ntok, 192, 0, stream>>>(ffn, top, rankb, xb16);
      gemm_h<128, 0, 0, 0><<<768, 256, 0, stream>>>(
          xb16, w13_16, gu, nullptr, 384, 4096, 768, 4096, 3, 32,
          (long long)384 * 768, (long long)4096 * 768, 1, (long long)384 * 4096, 0);
      silu_k<0><<<(Ec * CAPPc * Hc) / 256, 256, 0, stream>>>(gu, act16);
      gemm_h<64, 0, 0, 0><<<288, 256, 0, stream>>>(
          act16, w2_16, yexp, nullptr, 384, 768, 2048, 768, 3, 12,
          (long long)384 * 2048, (long long)768 * 2048, 1, (long long)384 * 768, 0);
    }
    gather_add<<<Ntok, 192, 0, stream>>>(hbuf, yexp, top, rankb, x, x16);
  }

  rmsnorm_h<<<Ntok, 256, 0, stream>>>(x, xf16, lnf);
  f2h4<<<(int)(((long long)Vc * 768 / 4 + 255) / 256), 256, 0, stream>>>(
      wte, wt16, (long long)Vc * 768 / 4);
  // logits = xf @ wte^T  (single fp16, N tail handled)
  gemm_h<128, 0, 0, 1><<<6288, 256, 0, stream>>>(
      xf16, wt16, out, nullptr, 2048, Vc, 768, Vc, 16, 393, 0, 0, 1, 0, 0);
  aux_fin<<<1, 64, 0, stream>>>(psum, cnt, z2, out + LOGITS_N);
}

// Round 5
// 1345.757 us; speedup vs baseline: 1.2774x; 1.1773x over previous
//
// LunarisCodex MoE-GPT forward, MI355X/gfx950. Round 5: split-GEMM restructure —
// stage Ah/Al/Bh/Bl planes once per k-slice, 3 MFMA terms per barrier (3x fewer
// barriers, 2/3 staging); non-split GEMMs BK=64; o_proj BN=64; fused qk-norm+rope.
#include <hip/hip_runtime.h>

typedef __attribute__((ext_vector_type(8))) _Float16 half8;
typedef __attribute__((ext_vector_type(4))) float f32x4;

constexpr int Bc = 2, Tc = 1024, Dc = 768, NHc = 12, HDc = 64;
constexpr int Vc = 50257, Lc = 2, Ec = 8, Hc = 2048;
constexpr int Ntok = Bc * Tc;            // 2048
constexpr int CAPc = 320, CAPPc = 384;   // capacity, padded rows per expert
constexpr long long LOGITS_N = (long long)Bc * Tc * Vc;  // 102926336

typedef const __attribute__((address_space(1))) unsigned int* gas_t;
typedef __attribute__((address_space(3))) unsigned int* las_t;
__device__ __forceinline__ void gload16(const void* g, void* l) {
  __builtin_amdgcn_global_load_lds((gas_t)g, (las_t)l, 16, 0, 0);
}

__device__ __forceinline__ void splitf16(float a, unsigned short& h, unsigned short& l) {
  _Float16 hh = (_Float16)a;                       // RNE
  _Float16 ll = (_Float16)(a - (float)hh);
  h = __builtin_bit_cast(unsigned short, hh);
  l = __builtin_bit_cast(unsigned short, ll);
}
__device__ __forceinline__ unsigned short f16o(float a) {
  _Float16 hh = (_Float16)a;
  return __builtin_bit_cast(unsigned short, hh);
}

// ---------------- small kernels ----------------

__global__ void zero_small(float* psum, float* z2) {
  int t = threadIdx.x;
  if (t < Lc * Ec) psum[t] = 0.f;
  if (t < Lc) z2[t] = 0.f;
}

// embed: x (f32) + x16 (split-fp16 [hi768|lo768])
__global__ void embed_k(const int* __restrict__ idx, const float* __restrict__ wte,
                        float* __restrict__ x, unsigned short* __restrict__ x16) {
  int n = blockIdx.x;
  long long v = idx[n];
  const float4* src = (const float4*)(wte + v * 768);
  float4* dst = (float4*)(x + (long long)n * 768);
  int t = threadIdx.x;
  if (t < 192) {
    float4 val = src[t];
    dst[t] = val;
    ushort4 h, l;
    splitf16(val.x, h.x, l.x); splitf16(val.y, h.y, l.y);
    splitf16(val.z, h.z, l.z); splitf16(val.w, h.w, l.w);
    unsigned short* d = x16 + (long long)n * 1536 + t * 4;
    *(ushort4*)d = h;
    *(ushort4*)(d + 768) = l;
  }
}

// f32 -> fp16 single (for wte)
__global__ void f2h4(const float* __restrict__ in, unsigned short* __restrict__ out,
                     long long n4) {
  long long i = (long long)blockIdx.x * 256 + threadIdx.x;
  if (i >= n4) return;
  float4 v = ((const float4*)in)[i];
  ushort4 o;
  o.x = f16o(v.x); o.y = f16o(v.y); o.z = f16o(v.z); o.w = f16o(v.w);
  ((ushort4*)out)[i] = o;
}

// f32 weights (K,N) -> fp16 transposed. SP=1: (N,2K) [hi|lo]; SP=0: (N,K) hi only.
template <int SP>
__global__ void __launch_bounds__(256) split2_wT(const float* __restrict__ src,
    unsigned short* __restrict__ dst, int K, int N, long long sS, long long sD) {
  __shared__ float t[32][33];
  int z = blockIdx.z;
  src += (long long)z * sS;
  dst += (long long)z * sD;
  int n0 = blockIdx.x * 32, k0 = blockIdx.y * 32;
  int tid = threadIdx.x;
  int r = tid >> 3, c4 = (tid & 7) * 4;
  float4 v = *(const float4*)(src + (long long)(k0 + r) * N + n0 + c4);
  t[r][c4 + 0] = v.x; t[r][c4 + 1] = v.y; t[r][c4 + 2] = v.z; t[r][c4 + 3] = v.w;
  __syncthreads();
  int n = tid >> 3, kq = (tid & 7) * 4;
  ushort4 h, l;
  splitf16(t[kq + 0][n], h.x, l.x);
  splitf16(t[kq + 1][n], h.y, l.y);
  splitf16(t[kq + 2][n], h.z, l.z);
  splitf16(t[kq + 3][n], h.w, l.w);
  const int lda = SP ? 2 * K : K;
  unsigned short* d = dst + (long long)(n0 + n) * lda + k0 + kq;
  *(ushort4*)d = h;
  if (SP) *(ushort4*)(d + K) = l;
}

// rmsnorm over 768 cols; strided in/out, f32 out
__global__ void __launch_bounds__(256) rmsnorm_k(const float* in, int istride,
                                                 float* outp, int ostride,
                                                 const float* w) {
  long long n = blockIdx.x;
  const float* xr = in + n * istride;
  float* yr = outp + n * ostride;
  int tid = threadIdx.x;
  float s = 0.f;
  for (int i = tid; i < 768; i += 256) { float v = xr[i]; s += v * v; }
  #pragma unroll
  for (int o = 32; o; o >>= 1) s += __shfl_down(s, o);
  __shared__ float red[4];
  __shared__ float bs;
  if ((tid & 63) == 0) red[tid >> 6] = s;
  __syncthreads();
  if (tid == 0) bs = rsqrtf((red[0] + red[1] + red[2] + red[3]) / 768.0f + 1e-5f);
  __syncthreads();
  float sc = bs;
  for (int i = tid; i < 768; i += 256) yr[i] = xr[i] * sc * w[i];
}

// rmsnorm -> fp16 single output (final ln before logits)
__global__ void __launch_bounds__(256) rmsnorm_h(const float* in,
                                                 unsigned short* outp, const float* w) {
  long long n = blockIdx.x;
  const float* xr = in + n * 768;
  unsigned short* yr = outp + n * 768;
  int tid = threadIdx.x;
  float s = 0.f;
  for (int i = tid; i < 768; i += 256) { float v = xr[i]; s += v * v; }
  #pragma unroll
  for (int o = 32; o; o >>= 1) s += __shfl_down(s, o);
  __shared__ float red[4];
  __shared__ float bs;
  if ((tid & 63) == 0) red[tid >> 6] = s;
  __syncthreads();
  if (tid == 0) bs = rsqrtf((red[0] + red[1] + red[2] + red[3]) / 768.0f + 1e-5f);
  __syncthreads();
  float sc = bs;
  for (int i = tid; i < 768; i += 256) yr[i] = f16o(xr[i] * sc * w[i]);
}

// fused q/k rmsnorm + RoPE + V pass-through. One block per token.
// qkv (N,2304) f32 -> qr,kr (z,1024,128=[hi64|lo64]) split-fp16,
// vr (z,64,2048=[hi1024|lo1024]) split-fp16 transposed.
__global__ void __launch_bounds__(256) qk_rope(const float* __restrict__ qkv,
    const float* __restrict__ qnw, const float* __restrict__ knw,
    unsigned short* __restrict__ qr, unsigned short* __restrict__ kr,
    unsigned short* __restrict__ vr) {
  int n = blockIdx.x;
  int t = n & 1023, b = n >> 10;
  const float* row = qkv + (long long)n * 2304;
  int tid = threadIdx.x;
  float sq = 0.f, sk = 0.f;
  for (int i = tid; i < 768; i += 256) {
    float q = row[i]; sq += q * q;
    float k = row[768 + i]; sk += k * k;
  }
  #pragma unroll
  for (int o = 32; o; o >>= 1) { sq += __shfl_down(sq, o); sk += __shfl_down(sk, o); }
  __shared__ float redq[4], redk[4];
  __shared__ float bq, bk;
  if ((tid & 63) == 0) { redq[tid >> 6] = sq; redk[tid >> 6] = sk; }
  __syncthreads();
  if (tid == 0) {
    bq = rsqrtf((redq[0] + redq[1] + redq[2] + redq[3]) / 768.0f + 1e-5f);
    bk = rsqrtf((redk[0] + redk[1] + redk[2] + redk[3]) / 768.0f + 1e-5f);
  }
  __syncthreads();
  float nq = bq, nk = bk;
  for (int i = tid; i < 384; i += 256) {
    int hh = i >> 5, j = i & 31;
    int c = hh * 64 + 2 * j;
    float ang = (float)t * powf(10000.0f, -((float)j * (1.0f / 32.0f)));
    float cs = cosf(ang), sn = sinf(ang);
    int z = b * 12 + hh;
    long long qb = ((long long)z * 1024 + t) * 128 + 2 * j;
    unsigned short h0, l0, h1, l1;
    float q0 = row[c] * nq * qnw[c], q1 = row[c + 1] * nq * qnw[c + 1];
    splitf16(q0 * cs - q1 * sn, h0, l0);
    splitf16(q0 * sn + q1 * cs, h1, l1);
    *(unsigned int*)&qr[qb] = (unsigned)h0 | ((unsigned)h1 << 16);
    *(unsigned int*)&qr[qb + 64] = (unsigned)l0 | ((unsigned)l1 << 16);
    float k0 = row[768 + c] * nk * knw[c], k1 = row[768 + c + 1] * nk * knw[c + 1];
    splitf16(k0 * cs - k1 * sn, h0, l0);
    splitf16(k0 * sn + k1 * cs, h1, l1);
    *(unsigned int*)&kr[qb] = (unsigned)h0 | ((unsigned)h1 << 16);
    *(unsigned int*)&kr[qb + 64] = (unsigned)l0 | ((unsigned)l1 << 16);
    splitf16(row[1536 + c], h0, l0);
    splitf16(row[1536 + c + 1], h1, l1);
    long long vb = ((long long)z * 64 + 2 * j) * 2048 + t;
    vr[vb] = h0; vr[vb + 1024] = l0;
    vr[vb + 2048] = h1; vr[vb + 3072] = l1;
  }
}

// ---------------- fused flash attention ----------------
__global__ void __launch_bounds__(256) flash_attn(
    const unsigned short* __restrict__ qr, const unsigned short* __restrict__ kr,
    const unsigned short* __restrict__ vr, unsigned short* __restrict__ yout) {
  __shared__ __align__(16) unsigned short Ph[4][16][72];
  __shared__ __align__(16) unsigned short Pl[4][16][72];
  int bid = blockIdx.x;
  int z = bid >> 4;
  int qt = 15 - (bid & 15);          // heavy tiles first (load balance)
  int b = z / 12, h = z % 12;
  int q0 = qt * 64;
  int wave = threadIdx.x >> 6, lane = threadIdx.x & 63;
  int lr = lane & 15, lg = lane >> 4;
  int qw = q0 + wave * 16;           // this wave's 16 q rows
  half8 af[2][2];
  const unsigned short* qbase = qr + ((long long)z * 1024 + qw + lr) * 128;
  #pragma unroll
  for (int ks = 0; ks < 2; ++ks)
    #pragma unroll
    for (int p = 0; p < 2; ++p)
      af[ks][p] = *(const half8*)(qbase + p * 64 + ks * 32 + lg * 8);
  f32x4 accy[4];
  #pragma unroll
  for (int df = 0; df < 4; ++df) accy[df] = (f32x4){0.f, 0.f, 0.f, 0.f};
  float mrun[4] = {-3.4e38f, -3.4e38f, -3.4e38f, -3.4e38f};
  float srun[4] = {0.f, 0.f, 0.f, 0.f};
  for (int kt = 0; kt <= qt; ++kt) {
    int kv0 = kt * 64;
    f32x4 s[4];
    #pragma unroll
    for (int nf = 0; nf < 4; ++nf) s[nf] = (f32x4){0.f, 0.f, 0.f, 0.f};
    const unsigned short* kbase = kr + ((long long)z * 1024 + kv0 + lr) * 128;
    #pragma unroll
    for (int nf = 0; nf < 4; ++nf) {
      const unsigned short* kb = kbase + nf * 16 * 128;
      #pragma unroll
      for (int ks = 0; ks < 2; ++ks) {
        half8 bh = *(const half8*)(kb + ks * 32 + lg * 8);
        half8 bl = *(const half8*)(kb + 64 + ks * 32 + lg * 8);
        s[nf] = __builtin_amdgcn_mfma_f32_16x16x32_f16(af[ks][0], bh, s[nf], 0, 0, 0);
        s[nf] = __builtin_amdgcn_mfma_f32_16x16x32_f16(af[ks][1], bh, s[nf], 0, 0, 0);
        s[nf] = __builtin_amdgcn_mfma_f32_16x16x32_f16(af[ks][0], bl, s[nf], 0, 0, 0);
      }
    }
    bool diag = (kt == qt);
    #pragma unroll
    for (int nf = 0; nf < 4; ++nf)
      #pragma unroll
      for (int j = 0; j < 4; ++j) {
        float v = s[nf][j] * 0.125f;
        if (diag && (nf * 16 + lr > wave * 16 + lg * 4 + j)) v = -1e30f;
        s[nf][j] = v;
      }
    #pragma unroll
    for (int j = 0; j < 4; ++j) {
      float tm = fmaxf(fmaxf(s[0][j], s[1][j]), fmaxf(s[2][j], s[3][j]));
      #pragma unroll
      for (int o = 1; o < 16; o <<= 1) tm = fmaxf(tm, __shfl_xor(tm, o));
      float mnew = fmaxf(mrun[j], tm);
      float sc = expf(mrun[j] - mnew);
      float ts = 0.f;
      #pragma unroll
      for (int nf = 0; nf < 4; ++nf) {
        float p = expf(s[nf][j] - mnew);
        ts += p;
        unsigned short ph, pl;
        splitf16(p, ph, pl);
        Ph[wave][lg * 4 + j][nf * 16 + lr] = ph;
        Pl[wave][lg * 4 + j][nf * 16 + lr] = pl;
      }
      #pragma unroll
      for (int o = 1; o < 16; o <<= 1) ts += __shfl_xor(ts, o);
      srun[j] = srun[j] * sc + ts;
      mrun[j] = mnew;
      #pragma unroll
      for (int df = 0; df < 4; ++df) accy[df][j] *= sc;
    }
    #pragma unroll
    for (int ks2 = 0; ks2 < 2; ++ks2) {
      half8 aph = *(const half8*)&Ph[wave][lr][ks2 * 32 + lg * 8];
      half8 apl = *(const half8*)&Pl[wave][lr][ks2 * 32 + lg * 8];
      #pragma unroll
      for (int df = 0; df < 4; ++df) {
        const unsigned short* vb =
            vr + ((long long)z * 64 + df * 16 + lr) * 2048 + kv0 + ks2 * 32 + lg * 8;
        half8 bvh = *(const half8*)vb;
        half8 bvl = *(const half8*)(vb + 1024);
        accy[df] = __builtin_amdgcn_mfma_f32_16x16x32_f16(aph, bvh, accy[df], 0, 0, 0);
        accy[df] = __builtin_amdgcn_mfma_f32_16x16x32_f16(apl, bvh, accy[df], 0, 0, 0);
        accy[df] = __builtin_amdgcn_mfma_f32_16x16x32_f16(aph, bvl, accy[df], 0, 0, 0);
      }
    }
  }
  float inv[4];
  #pragma unroll
  for (int j = 0; j < 4; ++j) inv[j] = 1.0f / srun[j];
  #pragma unroll
  for (int df = 0; df < 4; ++df)
    #pragma unroll
    for (int j = 0; j < 4; ++j) {
      long long tok = (long long)b * 1024 + qw + lg * 4 + j;
      int col = h * 64 + df * 16 + lr;
      unsigned short hh, ll;
      splitf16(accy[df][j] * inv[j], hh, ll);
      yout[tok * 1536 + col] = hh;
      yout[tok * 1536 + 768 + col] = ll;
    }
}

// gate: logits(f32), softmax probs, argmax (first-max), aux accumulators
__global__ void __launch_bounds__(256) gate_k(const float* __restrict__ xin,
    const float* __restrict__ gw, int* __restrict__ top,
    float* __restrict__ psum, float* __restrict__ z2) {
  __shared__ float gws[768 * 8];
  __shared__ float pacc[8];
  __shared__ float zacc;
  int tid = threadIdx.x;
  for (int i = tid; i < 768 * 8 / 4; i += 256) ((float4*)gws)[i] = ((const float4*)gw)[i];
  if (tid < 8) pacc[tid] = 0.f;
  if (tid == 0) zacc = 0.f;
  __syncthreads();
  int n = blockIdx.x * 256 + tid;
  const float4* xr4 = (const float4*)(xin + (long long)n * 768);
  float l[8] = {0, 0, 0, 0, 0, 0, 0, 0};
  for (int d4 = 0; d4 < 192; ++d4) {
    float4 xv = xr4[d4];
    const float* g = &gws[d4 * 32];
    #pragma unroll
    for (int e = 0; e < 8; ++e)
      l[e] += xv.x * g[e] + xv.y * g[8 + e] + xv.z * g[16 + e] + xv.w * g[24 + e];
  }
  float mx = l[0]; int bi = 0;
  #pragma unroll
  for (int e = 1; e < 8; ++e) if (l[e] > mx) { mx = l[e]; bi = e; }  // first-max
  float p[8]; float se = 0.f;
  #pragma unroll
  for (int e = 0; e < 8; ++e) { p[e] = expf(l[e] - mx); se += p[e]; }
  float z = mx + logf(se);
  top[n] = bi;
  #pragma unroll
  for (int e = 0; e < 8; ++e) atomicAdd(&pacc[e], p[e] / se);
  atomicAdd(&zacc, z * z);
  __syncthreads();
  if (tid < 8) atomicAdd(&psum[tid], pacc[tid]);
  if (tid == 0) atomicAdd(z2, zacc);
}

// single-wave rank scan (matches stable argsort arrival order)
__global__ void route_scan(const int* __restrict__ top, int* __restrict__ rank,
                           int* __restrict__ cnt) {
  int lane = threadIdx.x;
  int c[8] = {0, 0, 0, 0, 0, 0, 0, 0};
  unsigned long long below = (1ull << lane) - 1ull;
  for (int s = 0; s < Ntok / 64; ++s) {
    int n = s * 64 + lane;
    int e = top[n];
    int r = 0;
    #pragma unroll
    for (int q = 0; q < 8; ++q) {
      unsigned long long m = __ballot(e == q);
      if (e == q) r = c[q] + __popcll(m & below);
      c[q] += __popcll(m);
    }
    rank[n] = r;
  }
  #pragma unroll
  for (int q = 0; q < 8; ++q) if (lane == q) cnt[q] = c[q];
}

// ffn f32 -> xb16. SP=1: (row,1536=[hi|lo]); SP=0: (row,768) hi only.
template <int SP>
__global__ void scatter_xb(const float* __restrict__ xin, const int* __restrict__ top,
                           const int* __restrict__ rank, unsigned short* __restrict__ xb) {
  int n = blockIdx.x;
  int r = rank[n];
  if (r >= CAPc) return;
  int e = top[n];
  int t = threadIdx.x;
  if (t >= 192) return;
  float4 v = ((const float4*)(xin + (long long)n * 768))[t];
  ushort4 h, l;
  splitf16(v.x, h.x, l.x); splitf16(v.y, h.y, l.y);
  splitf16(v.z, h.z, l.z); splitf16(v.w, h.w, l.w);
  const int lda = SP ? 1536 : 768;
  unsigned short* dst = xb + ((long long)e * CAPPc + r) * lda + t * 4;
  *(ushort4*)dst = h;
  if (SP) *(ushort4*)(dst + 768) = l;
}

// gu f32 (rows,4096=[g|u]) -> act16. SP=1: (rows,4096=[hi2048|lo2048]); SP=0: (rows,2048).
template <int SP>
__global__ void __launch_bounds__(256) silu_k(const float* __restrict__ gu,
                                              unsigned short* __restrict__ act) {
  long long i = (long long)blockIdx.x * 256 + threadIdx.x;  // < E*CAPP*H
  long long row = i >> 11;
  int h = (int)(i & 2047);
  float g = gu[row * 4096 + h];
  float u = gu[row * 4096 + 2048 + h];
  float a = g / (1.f + expf(-g)) * u;
  if (SP) {
    unsigned short hh, ll;
    splitf16(a, hh, ll);
    act[row * 4096 + h] = hh;
    act[row * 4096 + 2048 + h] = ll;
  } else {
    act[row * 2048 + h] = f16o(a);
  }
}

// h + expert-out -> x (f32) AND x16 (split-fp16) for next layer
__global__ void gather_add(const float* __restrict__ h, const float* __restrict__ yexp,
                           const int* __restrict__ top, const int* __restrict__ rank,
                           float* __restrict__ xo, unsigned short* __restrict__ x16) {
  int n = blockIdx.x;
  int r = rank[n], e = top[n];
  bool kept = r < CAPc;
  int rc = kept ? r : (CAPc - 1);
  const float4* hs = (const float4*)(h + (long long)n * 768);
  const float4* ys = (const float4*)(yexp + ((long long)e * CAPPc + rc) * 768);
  float4* dst = (float4*)(xo + (long long)n * 768);
  int t = threadIdx.x;
  if (t < 192) {
    float4 v = hs[t];
    if (kept) { float4 y = ys[t]; v.x += y.x; v.y += y.y; v.z += y.z; v.w += y.w; }
    dst[t] = v;
    ushort4 hh, ll;
    splitf16(v.x, hh.x, ll.x); splitf16(v.y, hh.y, ll.y);
    splitf16(v.z, hh.z, ll.z); splitf16(v.w, hh.w, ll.w);
    unsigned short* d = x16 + (long long)n * 1536 + t * 4;
    *(ushort4*)d = hh;
    *(ushort4*)(d + 768) = ll;
  }
}

__global__ void aux_fin(const float* __restrict__ psum, const int* __restrict__ cnt,
                        const float* __restrict__ z2, float* __restrict__ outp) {
  if (threadIdx.x == 0) {
    float aux = 0.f;
    for (int l = 0; l < Lc; ++l) {
      float bl = 0.f;
      for (int e = 0; e < 8; ++e)
        bl += (psum[l * 8 + e] * (1.0f / 2048.0f)) * ((float)cnt[l * 8 + e] * (1.0f / 2048.0f));
      aux += bl * (0.01f * 8.0f) + (z2[l] * (1.0f / 2048.0f)) * 0.001f;
    }
    outp[0] = aux;
  }
}

// ---------------- fp16 MFMA GEMM (4-plane staging) ----------------
// C(M,N) f32 [+Add] = A @ Bt^T.  A:(M,lda) fp16, Bt:(N,lda) fp16 pre-transposed.
// SPLIT=1: [hi K|lo K] (lda=2K). Per 32-k-slice: stage Ah/Al/Bh/Bl planes, one
// barrier pair, 3 MFMA terms (AhBh+AlBh+AhBl). SPLIT=0: lda=K, BK=64 — planes
// hold k-slices s*64 and s*64+32, 2 MFMA per fragment.
template <int BN, int SPLIT, int ADD, int NTAIL>
__global__ void __launch_bounds__(256) gemm_h(
    const unsigned short* __restrict__ A, const unsigned short* __restrict__ Bt,
    float* __restrict__ C, const float* __restrict__ Add,
    int M, int N, int K, int ldc, int gx, int gy,
    long long sA, long long sB, int zdiv, long long sC1, long long sC2) {
  constexpr int FN = (BN == 128) ? 4 : 2;
  __shared__ __align__(16) unsigned short Ash[128 * 32];
  __shared__ __align__(16) unsigned short Asl[128 * 32];
  __shared__ __align__(16) unsigned short Bsh[BN * 32];
  __shared__ __align__(16) unsigned short Bsl[BN * 32];
  int tot = gridDim.x;
  int lin = blockIdx.x;
  if ((tot & 7) == 0) lin = (lin & 7) * (tot >> 3) + (lin >> 3);  // XCD chunking
  int pz = lin / (gx * gy);
  int r2 = lin - pz * (gx * gy);
  const int m0 = (r2 % gx) * 128, n0 = (r2 / gx) * BN;
  A += (long long)pz * sA;
  Bt += (long long)pz * sB;
  const long long co = (long long)(pz / zdiv) * sC1 + (long long)(pz % zdiv) * sC2;
  const int lda = SPLIT ? 2 * K : K;
  const int NS = SPLIT ? K / 32 : K / 64;
  const int tid = threadIdx.x;
  const int lane = tid & 63, wave = tid >> 6;
  const int wm = (BN == 128) ? (wave >> 1) : (wave & 1);
  const int wn = (BN == 128) ? (wave & 1) : (wave >> 1);
  const int srow = tid >> 2, scol = (tid & 3) * 8;
  const unsigned short* Ar = A + (long long)(m0 + srow) * lda + scol;
  int br0 = n0 + srow;
  if (NTAIL) br0 = min(br0, N - 1);
  const unsigned short* Br = Bt + (long long)br0 * lda + scol;
  int br1 = n0 + srow + 64;
  if (NTAIL) br1 = min(br1, N - 1);
  const unsigned short* Br2 = Bt + (long long)br1 * lda + scol;
  f32x4 acc[4][FN];
  #pragma unroll
  for (int m = 0; m < 4; ++m)
    #pragma unroll
    for (int n = 0; n < FN; ++n) acc[m][n] = (f32x4){0.f, 0.f, 0.f, 0.f};
  for (int s = 0; s < NS; ++s) {
    // plane offsets: SPLIT -> h-plane at ks, l-plane at K+ks (hi/lo of slice s)
    //                !SPLIT -> "h"=slice s*64, "l"=slice s*64+32
    const int kh = SPLIT ? s * 32 : s * 64;
    const int kl = SPLIT ? K + s * 32 : s * 64 + 32;
    gload16(Ar + kh, &Ash[wave * 512]);
    gload16(Ar + (long long)64 * lda + kh, &Ash[2048 + wave * 512]);
    gload16(Ar + kl, &Asl[wave * 512]);
    gload16(Ar + (long long)64 * lda + kl, &Asl[2048 + wave * 512]);
    gload16(Br + kh, &Bsh[wave * 512]);
    gload16(Br + kl, &Bsl[wave * 512]);
    if (BN == 128) {
      gload16(Br2 + kh, &Bsh[2048 + wave * 512]);
      gload16(Br2 + kl, &Bsl[2048 + wave * 512]);
    }
    __syncthreads();
    half8 bfh[FN], bfl[FN];
    #pragma unroll
    for (int n = 0; n < FN; ++n) {
      int bo = (wn * (FN * 16) + n * 16 + (lane & 15)) * 32 + (lane >> 4) * 8;
      bfh[n] = *(const half8*)&Bsh[bo];
      bfl[n] = *(const half8*)&Bsl[bo];
    }
    #pragma unroll
    for (int m = 0; m < 4; ++m) {
      int ao = (wm * 64 + m * 16 + (lane & 15)) * 32 + (lane >> 4) * 8;
      half8 afh = *(const half8*)&Ash[ao];
      half8 afl = *(const half8*)&Asl[ao];
      #pragma unroll
      for (int n = 0; n < FN; ++n) {
        acc[m][n] = __builtin_amdgcn_mfma_f32_16x16x32_f16(afh, bfh[n], acc[m][n], 0, 0, 0);
        if (SPLIT) {
          acc[m][n] = __builtin_amdgcn_mfma_f32_16x16x32_f16(afl, bfh[n], acc[m][n], 0, 0, 0);
          acc[m][n] = __builtin_amdgcn_mfma_f32_16x16x32_f16(afh, bfl[n], acc[m][n], 0, 0, 0);
        } else {
          acc[m][n] = __builtin_amdgcn_mfma_f32_16x16x32_f16(afl, bfl[n], acc[m][n], 0, 0, 0);
        }
      }
    }
    __syncthreads();
  }
  #pragma unroll
  for (int m = 0; m < 4; ++m)
    #pragma unroll
    for (int n = 0; n < FN; ++n) {
      int col = n0 + wn * (FN * 16) + n * 16 + (lane & 15);
      if (!NTAIL || col < N) {
        #pragma unroll
        for (int j = 0; j < 4; ++j) {
          long long row = m0 + wm * 64 + m * 16 + (lane >> 4) * 4 + j;
          long long o = co + row * ldc + col;
          float v = acc[m][n][j];
          if (ADD) v += Add[o];
          C[o] = v;
        }
      }
    }
}

// ---------------- host launch ----------------

extern "C" void kernel_launch(void* const* d_in, const int* in_sizes, int n_in,
                              void* d_out, int out_size, void* d_ws, size_t ws_size,
                              hipStream_t stream) {
  (void)in_sizes; (void)n_in; (void)out_size; (void)ws_size;
  const int*   idx   = (const int*)d_in[0];
  const float* wte   = (const float*)d_in[1];
  const float* wqkv  = (const float*)d_in[2];
  const float* qnw   = (const float*)d_in[3];
  const float* knw   = (const float*)d_in[4];
  const float* oproj = (const float*)d_in[5];
  const float* ffnw  = (const float*)d_in[6];
  const float* gatew = (const float*)d_in[7];
  const float* w13   = (const float*)d_in[8];
  const float* w2p   = (const float*)d_in[9];
  const float* lnf   = (const float*)d_in[10];
  float* out = (float*)d_out;

  char* base = (char*)d_ws;
  size_t off = 0;
  auto alloc = [&](size_t bytes) -> char* {
    off = (off + 255) & ~(size_t)255;
    char* p = base + off; off += bytes; return p;
  };
  float* x     = (float*)alloc((size_t)Ntok * 768 * 4);
  float* qkv   = (float*)alloc((size_t)Ntok * 2304 * 4);
  float* hbuf  = (float*)alloc((size_t)Ntok * 768 * 4);
  float* ffn   = (float*)alloc((size_t)Ntok * 768 * 4);
  unsigned short* x16   = (unsigned short*)alloc((size_t)Ntok * 1536 * 2);
  unsigned short* yfl16 = (unsigned short*)alloc((size_t)Ntok * 1536 * 2);
  unsigned short* qr16  = (unsigned short*)alloc((size_t)24 * 1024 * 128 * 2);
  unsigned short* kr16  = (unsigned short*)alloc((size_t)24 * 1024 * 128 * 2);
  unsigned short* vr16  = (unsigned short*)alloc((size_t)24 * 64 * 2048 * 2);
  unsigned short* xb16  = (unsigned short*)alloc((size_t)Ec * CAPPc * 1536 * 2);
  unsigned short* wo16  = (unsigned short*)alloc((size_t)768 * 1536 * 2);
  unsigned short* xf16  = (unsigned short*)alloc((size_t)Ntok * 768 * 2);
  char* spb = alloc((size_t)24 * 1024 * 1024 * 4);           // scratch region
  float* gu   = (float*)spb;                                 // [0, 50.3M)
  float* yexp = (float*)spb;                                 // [0, 9.4M) over dead gu
  unsigned short* act16 = (unsigned short*)(spb + 50331648); // [50.3M, 75.5M)
  unsigned short* wq16  = (unsigned short*)(spb + 75497472); // [75.5M, 82.6M)
  unsigned short* w13_16 = (unsigned short*)alloc((size_t)Ec * 4096 * 1536 * 2); // 100.66MB
  unsigned short* wt16   = w13_16;                           // alias (used after)
  unsigned short* w2_16  = (unsigned short*)alloc((size_t)Ec * 768 * 4096 * 2);  // 50.3MB
  int* top    = (int*)alloc(Ntok * 4);
  int* rankb  = (int*)alloc(Ntok * 4);
  int* cnt    = (int*)alloc(Lc * Ec * 4);
  float* psum = (float*)alloc(Lc * Ec * 4);
  float* z2   = (float*)alloc(Lc * 4);

  zero_small<<<1, 64, 0, stream>>>(psum, z2);
  embed_k<<<Ntok, 192, 0, stream>>>(idx, wte, x, x16);

  for (int l = 0; l < Lc; ++l) {
    split2_wT<1><<<dim3(72, 24, 1), 256, 0, stream>>>(wqkv + (size_t)l * 768 * 2304, wq16,
                                                      768, 2304, 0, 0);
    split2_wT<1><<<dim3(24, 24, 1), 256, 0, stream>>>(oproj + (size_t)l * 768 * 768, wo16,
                                                      768, 768, 0, 0);
    if (l == 0) {
      split2_wT<1><<<dim3(128, 24, 8), 256, 0, stream>>>(w13, w13_16,
          768, 4096, (long long)768 * 4096, (long long)4096 * 1536);
      split2_wT<1><<<dim3(24, 64, 8), 256, 0, stream>>>(w2p, w2_16,
          2048, 768, (long long)2048 * 768, (long long)768 * 4096);
    } else {
      split2_wT<0><<<dim3(128, 24, 8), 256, 0, stream>>>(w13 + (size_t)Ec * 768 * 4096, w13_16,
          768, 4096, (long long)768 * 4096, (long long)4096 * 768);
      split2_wT<0><<<dim3(24, 64, 8), 256, 0, stream>>>(w2p + (size_t)Ec * 2048 * 768, w2_16,
          2048, 768, (long long)2048 * 768, (long long)768 * 2048);
    }
    // qkv = x @ wqkv[l]
    gemm_h<128, 1, 0, 0><<<288, 256, 0, stream>>>(
        x16, wq16, qkv, nullptr, 2048, 2304, 768, 2304, 16, 18, 0, 0, 1, 0, 0);
    // fused q/k rmsnorm + rope + V transpose
    qk_rope<<<Ntok, 256, 0, stream>>>(qkv, qnw + l * 768, knw + l * 768, qr16, kr16, vr16);
    // fused attention -> yfl16 (split-fp16)
    flash_attn<<<384, 256, 0, stream>>>(qr16, kr16, vr16, yfl16);
    // h = x + y @ o_proj[l]
    gemm_h<64, 1, 1, 0><<<192, 256, 0, stream>>>(
        yfl16, wo16, hbuf, x, 2048, 768, 768, 768, 16, 12, 0, 0, 1, 0, 0);
    rmsnorm_k<<<Ntok, 256, 0, stream>>>(hbuf, 768, ffn, 768, ffnw + l * 768);
    gate_k<<<Ntok / 256, 256, 0, stream>>>(ffn, gatew + (size_t)l * 768 * 8, top,
                                           psum + l * 8, z2 + l);
    route_scan<<<1, 64, 0, stream>>>(top, rankb, cnt + l * 8);
    if (l == 0) {
      scatter_xb<1><<<Ntok, 192, 0, stream>>>(ffn, top, rankb, xb16);
      gemm_h<128, 1, 0, 0><<<768, 256, 0, stream>>>(
          xb16, w13_16, gu, nullptr, 384, 4096, 768, 4096, 3, 32,
          (long long)384 * 1536, (long long)4096 * 1536, 1, (long long)384 * 4096, 0);
      silu_k<1><<<(Ec * CAPPc * Hc) / 256, 256, 0, stream>>>(gu, act16);
      gemm_h<64, 1, 0, 0><<<288, 256, 0, stream>>>(
          act16, w2_16, yexp, nullptr, 384, 768, 2048, 768, 3, 12,
          (long long)384 * 4096, (long long)768 * 4096, 1, (long long)384 * 768, 0);
    } else {
      scatter_xb<0><<<Ntok, 192, 0, stream>>>(ffn, top, rankb, xb16);
      gemm_h<128, 0, 0, 0><<<768, 256, 0, stream>>>(
          xb16, w13_16, gu, nullptr, 384, 4096, 768, 4096, 3, 32,
          (long long)384 * 768, (long long)4096 * 768, 1, (long long)384 * 4096, 0);
      silu_k<0><<<(Ec * CAPPc * Hc) / 256, 256, 0, stream>>>(gu, act16);
      gemm_h<64, 0, 0, 0><<<288, 256, 0, stream>>>(
          act16, w2_16, yexp, nullptr, 384, 768, 2048, 768, 3, 12,
          (long long)384 * 2048, (long long)768 * 2048, 1, (long long)384 * 768, 0);
    }
    gather_add<<<Ntok, 192, 0, stream>>>(hbuf, yexp, top, rankb, x, x16);
  }

  rmsnorm_h<<<Ntok, 256, 0, stream>>>(x, xf16, lnf);
  f2h4<<<(int)(((long long)Vc * 768 / 4 + 255) / 256), 256, 0, stream>>>(
      wte, wt16, (long long)Vc * 768 / 4);
  // logits = xf @ wte^T  (single fp16, BK=64, N tail handled)
  gemm_h<128, 0, 0, 1><<<6288, 256, 0, stream>>>(
      xf16, wt16, out, nullptr, 2048, Vc, 768, Vc, 16, 393, 0, 0, 1, 0, 0);
  aux_fin<<<1, 64, 0, stream>>>(psum, cnt, z2, out + LOGITS_N);
}

// Round 6
// 1335.737 us; speedup vs baseline: 1.2870x; 1.0075x over previous
//
// LunarisCodex MoE-GPT forward, MI355X/gfx950. Round 6: double-buffered K-loop
// in gemm_h (prefetch-before-compute, 1 barrier/step, T3-minimal) + setprio.
#include <hip/hip_runtime.h>

typedef __attribute__((ext_vector_type(8))) _Float16 half8;
typedef __attribute__((ext_vector_type(4))) float f32x4;

constexpr int Bc = 2, Tc = 1024, Dc = 768, NHc = 12, HDc = 64;
constexpr int Vc = 50257, Lc = 2, Ec = 8, Hc = 2048;
constexpr int Ntok = Bc * Tc;            // 2048
constexpr int CAPc = 320, CAPPc = 384;   // capacity, padded rows per expert
constexpr long long LOGITS_N = (long long)Bc * Tc * Vc;  // 102926336

typedef const __attribute__((address_space(1))) unsigned int* gas_t;
typedef __attribute__((address_space(3))) unsigned int* las_t;
__device__ __forceinline__ void gload16(const void* g, void* l) {
  __builtin_amdgcn_global_load_lds((gas_t)g, (las_t)l, 16, 0, 0);
}

__device__ __forceinline__ void splitf16(float a, unsigned short& h, unsigned short& l) {
  _Float16 hh = (_Float16)a;                       // RNE
  _Float16 ll = (_Float16)(a - (float)hh);
  h = __builtin_bit_cast(unsigned short, hh);
  l = __builtin_bit_cast(unsigned short, ll);
}
__device__ __forceinline__ unsigned short f16o(float a) {
  _Float16 hh = (_Float16)a;
  return __builtin_bit_cast(unsigned short, hh);
}

// ---------------- small kernels ----------------

__global__ void zero_small(float* psum, float* z2) {
  int t = threadIdx.x;
  if (t < Lc * Ec) psum[t] = 0.f;
  if (t < Lc) z2[t] = 0.f;
}

// embed: x (f32) + x16 (split-fp16 [hi768|lo768])
__global__ void embed_k(const int* __restrict__ idx, const float* __restrict__ wte,
                        float* __restrict__ x, unsigned short* __restrict__ x16) {
  int n = blockIdx.x;
  long long v = idx[n];
  const float4* src = (const float4*)(wte + v * 768);
  float4* dst = (float4*)(x + (long long)n * 768);
  int t = threadIdx.x;
  if (t < 192) {
    float4 val = src[t];
    dst[t] = val;
    ushort4 h, l;
    splitf16(val.x, h.x, l.x); splitf16(val.y, h.y, l.y);
    splitf16(val.z, h.z, l.z); splitf16(val.w, h.w, l.w);
    unsigned short* d = x16 + (long long)n * 1536 + t * 4;
    *(ushort4*)d = h;
    *(ushort4*)(d + 768) = l;
  }
}

// f32 -> fp16 single (for wte)
__global__ void f2h4(const float* __restrict__ in, unsigned short* __restrict__ out,
                     long long n4) {
  long long i = (long long)blockIdx.x * 256 + threadIdx.x;
  if (i >= n4) return;
  float4 v = ((const float4*)in)[i];
  ushort4 o;
  o.x = f16o(v.x); o.y = f16o(v.y); o.z = f16o(v.z); o.w = f16o(v.w);
  ((ushort4*)out)[i] = o;
}

// f32 weights (K,N) -> fp16 transposed. SP=1: (N,2K) [hi|lo]; SP=0: (N,K) hi only.
template <int SP>
__global__ void __launch_bounds__(256) split2_wT(const float* __restrict__ src,
    unsigned short* __restrict__ dst, int K, int N, long long sS, long long sD) {
  __shared__ float t[32][33];
  int z = blockIdx.z;
  src += (long long)z * sS;
  dst += (long long)z * sD;
  int n0 = blockIdx.x * 32, k0 = blockIdx.y * 32;
  int tid = threadIdx.x;
  int r = tid >> 3, c4 = (tid & 7) * 4;
  float4 v = *(const float4*)(src + (long long)(k0 + r) * N + n0 + c4);
  t[r][c4 + 0] = v.x; t[r][c4 + 1] = v.y; t[r][c4 + 2] = v.z; t[r][c4 + 3] = v.w;
  __syncthreads();
  int n = tid >> 3, kq = (tid & 7) * 4;
  ushort4 h, l;
  splitf16(t[kq + 0][n], h.x, l.x);
  splitf16(t[kq + 1][n], h.y, l.y);
  splitf16(t[kq + 2][n], h.z, l.z);
  splitf16(t[kq + 3][n], h.w, l.w);
  const int lda = SP ? 2 * K : K;
  unsigned short* d = dst + (long long)(n0 + n) * lda + k0 + kq;
  *(ushort4*)d = h;
  if (SP) *(ushort4*)(d + K) = l;
}

// rmsnorm over 768 cols; strided in/out, f32 out
__global__ void __launch_bounds__(256) rmsnorm_k(const float* in, int istride,
                                                 float* outp, int ostride,
                                                 const float* w) {
  long long n = blockIdx.x;
  const float* xr = in + n * istride;
  float* yr = outp + n * ostride;
  int tid = threadIdx.x;
  float s = 0.f;
  for (int i = tid; i < 768; i += 256) { float v = xr[i]; s += v * v; }
  #pragma unroll
  for (int o = 32; o; o >>= 1) s += __shfl_down(s, o);
  __shared__ float red[4];
  __shared__ float bs;
  if ((tid & 63) == 0) red[tid >> 6] = s;
  __syncthreads();
  if (tid == 0) bs = rsqrtf((red[0] + red[1] + red[2] + red[3]) / 768.0f + 1e-5f);
  __syncthreads();
  float sc = bs;
  for (int i = tid; i < 768; i += 256) yr[i] = xr[i] * sc * w[i];
}

// rmsnorm -> fp16 single output (final ln before logits)
__global__ void __launch_bounds__(256) rmsnorm_h(const float* in,
                                                 unsigned short* outp, const float* w) {
  long long n = blockIdx.x;
  const float* xr = in + n * 768;
  unsigned short* yr = outp + n * 768;
  int tid = threadIdx.x;
  float s = 0.f;
  for (int i = tid; i < 768; i += 256) { float v = xr[i]; s += v * v; }
  #pragma unroll
  for (int o = 32; o; o >>= 1) s += __shfl_down(s, o);
  __shared__ float red[4];
  __shared__ float bs;
  if ((tid & 63) == 0) red[tid >> 6] = s;
  __syncthreads();
  if (tid == 0) bs = rsqrtf((red[0] + red[1] + red[2] + red[3]) / 768.0f + 1e-5f);
  __syncthreads();
  float sc = bs;
  for (int i = tid; i < 768; i += 256) yr[i] = f16o(xr[i] * sc * w[i]);
}

// fused q/k rmsnorm + RoPE + V transpose. One block per token.
__global__ void __launch_bounds__(256) qk_rope(const float* __restrict__ qkv,
    const float* __restrict__ qnw, const float* __restrict__ knw,
    unsigned short* __restrict__ qr, unsigned short* __restrict__ kr,
    unsigned short* __restrict__ vr) {
  int n = blockIdx.x;
  int t = n & 1023, b = n >> 10;
  const float* row = qkv + (long long)n * 2304;
  int tid = threadIdx.x;
  float sq = 0.f, sk = 0.f;
  for (int i = tid; i < 768; i += 256) {
    float q = row[i]; sq += q * q;
    float k = row[768 + i]; sk += k * k;
  }
  #pragma unroll
  for (int o = 32; o; o >>= 1) { sq += __shfl_down(sq, o); sk += __shfl_down(sk, o); }
  __shared__ float redq[4], redk[4];
  __shared__ float bq, bk;
  if ((tid & 63) == 0) { redq[tid >> 6] = sq; redk[tid >> 6] = sk; }
  __syncthreads();
  if (tid == 0) {
    bq = rsqrtf((redq[0] + redq[1] + redq[2] + redq[3]) / 768.0f + 1e-5f);
    bk = rsqrtf((redk[0] + redk[1] + redk[2] + redk[3]) / 768.0f + 1e-5f);
  }
  __syncthreads();
  float nq = bq, nk = bk;
  for (int i = tid; i < 384; i += 256) {
    int hh = i >> 5, j = i & 31;
    int c = hh * 64 + 2 * j;
    float ang = (float)t * powf(10000.0f, -((float)j * (1.0f / 32.0f)));
    float cs = cosf(ang), sn = sinf(ang);
    int z = b * 12 + hh;
    long long qb = ((long long)z * 1024 + t) * 128 + 2 * j;
    unsigned short h0, l0, h1, l1;
    float q0 = row[c] * nq * qnw[c], q1 = row[c + 1] * nq * qnw[c + 1];
    splitf16(q0 * cs - q1 * sn, h0, l0);
    splitf16(q0 * sn + q1 * cs, h1, l1);
    *(unsigned int*)&qr[qb] = (unsigned)h0 | ((unsigned)h1 << 16);
    *(unsigned int*)&qr[qb + 64] = (unsigned)l0 | ((unsigned)l1 << 16);
    float k0 = row[768 + c] * nk * knw[c], k1 = row[768 + c + 1] * nk * knw[c + 1];
    splitf16(k0 * cs - k1 * sn, h0, l0);
    splitf16(k0 * sn + k1 * cs, h1, l1);
    *(unsigned int*)&kr[qb] = (unsigned)h0 | ((unsigned)h1 << 16);
    *(unsigned int*)&kr[qb + 64] = (unsigned)l0 | ((unsigned)l1 << 16);
    splitf16(row[1536 + c], h0, l0);
    splitf16(row[1536 + c + 1], h1, l1);
    long long vb = ((long long)z * 64 + 2 * j) * 2048 + t;
    vr[vb] = h0; vr[vb + 1024] = l0;
    vr[vb + 2048] = h1; vr[vb + 3072] = l1;
  }
}

// ---------------- fused flash attention ----------------
__global__ void __launch_bounds__(256) flash_attn(
    const unsigned short* __restrict__ qr, const unsigned short* __restrict__ kr,
    const unsigned short* __restrict__ vr, unsigned short* __restrict__ yout) {
  __shared__ __align__(16) unsigned short Ph[4][16][72];
  __shared__ __align__(16) unsigned short Pl[4][16][72];
  int bid = blockIdx.x;
  int z = bid >> 4;
  int qt = 15 - (bid & 15);          // heavy tiles first (load balance)
  int b = z / 12, h = z % 12;
  int q0 = qt * 64;
  int wave = threadIdx.x >> 6, lane = threadIdx.x & 63;
  int lr = lane & 15, lg = lane >> 4;
  int qw = q0 + wave * 16;           // this wave's 16 q rows
  half8 af[2][2];
  const unsigned short* qbase = qr + ((long long)z * 1024 + qw + lr) * 128;
  #pragma unroll
  for (int ks = 0; ks < 2; ++ks)
    #pragma unroll
    for (int p = 0; p < 2; ++p)
      af[ks][p] = *(const half8*)(qbase + p * 64 + ks * 32 + lg * 8);
  f32x4 accy[4];
  #pragma unroll
  for (int df = 0; df < 4; ++df) accy[df] = (f32x4){0.f, 0.f, 0.f, 0.f};
  float mrun[4] = {-3.4e38f, -3.4e38f, -3.4e38f, -3.4e38f};
  float srun[4] = {0.f, 0.f, 0.f, 0.f};
  for (int kt = 0; kt <= qt; ++kt) {
    int kv0 = kt * 64;
    f32x4 s[4];
    #pragma unroll
    for (int nf = 0; nf < 4; ++nf) s[nf] = (f32x4){0.f, 0.f, 0.f, 0.f};
    const unsigned short* kbase = kr + ((long long)z * 1024 + kv0 + lr) * 128;
    #pragma unroll
    for (int nf = 0; nf < 4; ++nf) {
      const unsigned short* kb = kbase + nf * 16 * 128;
      #pragma unroll
      for (int ks = 0; ks < 2; ++ks) {
        half8 bh = *(const half8*)(kb + ks * 32 + lg * 8);
        half8 bl = *(const half8*)(kb + 64 + ks * 32 + lg * 8);
        s[nf] = __builtin_amdgcn_mfma_f32_16x16x32_f16(af[ks][0], bh, s[nf], 0, 0, 0);
        s[nf] = __builtin_amdgcn_mfma_f32_16x16x32_f16(af[ks][1], bh, s[nf], 0, 0, 0);
        s[nf] = __builtin_amdgcn_mfma_f32_16x16x32_f16(af[ks][0], bl, s[nf], 0, 0, 0);
      }
    }
    bool diag = (kt == qt);
    #pragma unroll
    for (int nf = 0; nf < 4; ++nf)
      #pragma unroll
      for (int j = 0; j < 4; ++j) {
        float v = s[nf][j] * 0.125f;
        if (diag && (nf * 16 + lr > wave * 16 + lg * 4 + j)) v = -1e30f;
        s[nf][j] = v;
      }
    #pragma unroll
    for (int j = 0; j < 4; ++j) {
      float tm = fmaxf(fmaxf(s[0][j], s[1][j]), fmaxf(s[2][j], s[3][j]));
      #pragma unroll
      for (int o = 1; o < 16; o <<= 1) tm = fmaxf(tm, __shfl_xor(tm, o));
      float mnew = fmaxf(mrun[j], tm);
      float sc = expf(mrun[j] - mnew);
      float ts = 0.f;
      #pragma unroll
      for (int nf = 0; nf < 4; ++nf) {
        float p = expf(s[nf][j] - mnew);
        ts += p;
        unsigned short ph, pl;
        splitf16(p, ph, pl);
        Ph[wave][lg * 4 + j][nf * 16 + lr] = ph;
        Pl[wave][lg * 4 + j][nf * 16 + lr] = pl;
      }
      #pragma unroll
      for (int o = 1; o < 16; o <<= 1) ts += __shfl_xor(ts, o);
      srun[j] = srun[j] * sc + ts;
      mrun[j] = mnew;
      #pragma unroll
      for (int df = 0; df < 4; ++df) accy[df][j] *= sc;
    }
    #pragma unroll
    for (int ks2 = 0; ks2 < 2; ++ks2) {
      half8 aph = *(const half8*)&Ph[wave][lr][ks2 * 32 + lg * 8];
      half8 apl = *(const half8*)&Pl[wave][lr][ks2 * 32 + lg * 8];
      #pragma unroll
      for (int df = 0; df < 4; ++df) {
        const unsigned short* vb =
            vr + ((long long)z * 64 + df * 16 + lr) * 2048 + kv0 + ks2 * 32 + lg * 8;
        half8 bvh = *(const half8*)vb;
        half8 bvl = *(const half8*)(vb + 1024);
        accy[df] = __builtin_amdgcn_mfma_f32_16x16x32_f16(aph, bvh, accy[df], 0, 0, 0);
        accy[df] = __builtin_amdgcn_mfma_f32_16x16x32_f16(apl, bvh, accy[df], 0, 0, 0);
        accy[df] = __builtin_amdgcn_mfma_f32_16x16x32_f16(aph, bvl, accy[df], 0, 0, 0);
      }
    }
  }
  float inv[4];
  #pragma unroll
  for (int j = 0; j < 4; ++j) inv[j] = 1.0f / srun[j];
  #pragma unroll
  for (int df = 0; df < 4; ++df)
    #pragma unroll
    for (int j = 0; j < 4; ++j) {
      long long tok = (long long)b * 1024 + qw + lg * 4 + j;
      int col = h * 64 + df * 16 + lr;
      unsigned short hh, ll;
      splitf16(accy[df][j] * inv[j], hh, ll);
      yout[tok * 1536 + col] = hh;
      yout[tok * 1536 + 768 + col] = ll;
    }
}

// gate: logits(f32), softmax probs, argmax (first-max), aux accumulators
__global__ void __launch_bounds__(256) gate_k(const float* __restrict__ xin,
    const float* __restrict__ gw, int* __restrict__ top,
    float* __restrict__ psum, float* __restrict__ z2) {
  __shared__ float gws[768 * 8];
  __shared__ float pacc[8];
  __shared__ float zacc;
  int tid = threadIdx.x;
  for (int i = tid; i < 768 * 8 / 4; i += 256) ((float4*)gws)[i] = ((const float4*)gw)[i];
  if (tid < 8) pacc[tid] = 0.f;
  if (tid == 0) zacc = 0.f;
  __syncthreads();
  int n = blockIdx.x * 256 + tid;
  const float4* xr4 = (const float4*)(xin + (long long)n * 768);
  float l[8] = {0, 0, 0, 0, 0, 0, 0, 0};
  for (int d4 = 0; d4 < 192; ++d4) {
    float4 xv = xr4[d4];
    const float* g = &gws[d4 * 32];
    #pragma unroll
    for (int e = 0; e < 8; ++e)
      l[e] += xv.x * g[e] + xv.y * g[8 + e] + xv.z * g[16 + e] + xv.w * g[24 + e];
  }
  float mx = l[0]; int bi = 0;
  #pragma unroll
  for (int e = 1; e < 8; ++e) if (l[e] > mx) { mx = l[e]; bi = e; }  // first-max
  float p[8]; float se = 0.f;
  #pragma unroll
  for (int e = 0; e < 8; ++e) { p[e] = expf(l[e] - mx); se += p[e]; }
  float z = mx + logf(se);
  top[n] = bi;
  #pragma unroll
  for (int e = 0; e < 8; ++e) atomicAdd(&pacc[e], p[e] / se);
  atomicAdd(&zacc, z * z);
  __syncthreads();
  if (tid < 8) atomicAdd(&psum[tid], pacc[tid]);
  if (tid == 0) atomicAdd(z2, zacc);
}

// single-wave rank scan (matches stable argsort arrival order)
__global__ void route_scan(const int* __restrict__ top, int* __restrict__ rank,
                           int* __restrict__ cnt) {
  int lane = threadIdx.x;
  int c[8] = {0, 0, 0, 0, 0, 0, 0, 0};
  unsigned long long below = (1ull << lane) - 1ull;
  for (int s = 0; s < Ntok / 64; ++s) {
    int n = s * 64 + lane;
    int e = top[n];
    int r = 0;
    #pragma unroll
    for (int q = 0; q < 8; ++q) {
      unsigned long long m = __ballot(e == q);
      if (e == q) r = c[q] + __popcll(m & below);
      c[q] += __popcll(m);
    }
    rank[n] = r;
  }
  #pragma unroll
  for (int q = 0; q < 8; ++q) if (lane == q) cnt[q] = c[q];
}

// ffn f32 -> xb16. SP=1: (row,1536=[hi|lo]); SP=0: (row,768) hi only.
template <int SP>
__global__ void scatter_xb(const float* __restrict__ xin, const int* __restrict__ top,
                           const int* __restrict__ rank, unsigned short* __restrict__ xb) {
  int n = blockIdx.x;
  int r = rank[n];
  if (r >= CAPc) return;
  int e = top[n];
  int t = threadIdx.x;
  if (t >= 192) return;
  float4 v = ((const float4*)(xin + (long long)n * 768))[t];
  ushort4 h, l;
  splitf16(v.x, h.x, l.x); splitf16(v.y, h.y, l.y);
  splitf16(v.z, h.z, l.z); splitf16(v.w, h.w, l.w);
  const int lda = SP ? 1536 : 768;
  unsigned short* dst = xb + ((long long)e * CAPPc + r) * lda + t * 4;
  *(ushort4*)dst = h;
  if (SP) *(ushort4*)(dst + 768) = l;
}

// gu f32 (rows,4096=[g|u]) -> act16. SP=1: (rows,4096=[hi2048|lo2048]); SP=0: (rows,2048).
template <int SP>
__global__ void __launch_bounds__(256) silu_k(const float* __restrict__ gu,
                                              unsigned short* __restrict__ act) {
  long long i = (long long)blockIdx.x * 256 + threadIdx.x;  // < E*CAPP*H
  long long row = i >> 11;
  int h = (int)(i & 2047);
  float g = gu[row * 4096 + h];
  float u = gu[row * 4096 + 2048 + h];
  float a = g / (1.f + expf(-g)) * u;
  if (SP) {
    unsigned short hh, ll;
    splitf16(a, hh, ll);
    act[row * 4096 + h] = hh;
    act[row * 4096 + 2048 + h] = ll;
  } else {
    act[row * 2048 + h] = f16o(a);
  }
}

// h + expert-out -> x (f32) AND x16 (split-fp16) for next layer
__global__ void gather_add(const float* __restrict__ h, const float* __restrict__ yexp,
                           const int* __restrict__ top, const int* __restrict__ rank,
                           float* __restrict__ xo, unsigned short* __restrict__ x16) {
  int n = blockIdx.x;
  int r = rank[n], e = top[n];
  bool kept = r < CAPc;
  int rc = kept ? r : (CAPc - 1);
  const float4* hs = (const float4*)(h + (long long)n * 768);
  const float4* ys = (const float4*)(yexp + ((long long)e * CAPPc + rc) * 768);
  float4* dst = (float4*)(xo + (long long)n * 768);
  int t = threadIdx.x;
  if (t < 192) {
    float4 v = hs[t];
    if (kept) { float4 y = ys[t]; v.x += y.x; v.y += y.y; v.z += y.z; v.w += y.w; }
    dst[t] = v;
    ushort4 hh, ll;
    splitf16(v.x, hh.x, ll.x); splitf16(v.y, hh.y, ll.y);
    splitf16(v.z, hh.z, ll.z); splitf16(v.w, hh.w, ll.w);
    unsigned short* d = x16 + (long long)n * 1536 + t * 4;
    *(ushort4*)d = hh;
    *(ushort4*)(d + 768) = ll;
  }
}

__global__ void aux_fin(const float* __restrict__ psum, const int* __restrict__ cnt,
                        const float* __restrict__ z2, float* __restrict__ outp) {
  if (threadIdx.x == 0) {
    float aux = 0.f;
    for (int l = 0; l < Lc; ++l) {
      float bl = 0.f;
      for (int e = 0; e < 8; ++e)
        bl += (psum[l * 8 + e] * (1.0f / 2048.0f)) * ((float)cnt[l * 8 + e] * (1.0f / 2048.0f));
      aux += bl * (0.01f * 8.0f) + (z2[l] * (1.0f / 2048.0f)) * 0.001f;
    }
    outp[0] = aux;
  }
}

// ---------------- fp16 MFMA GEMM (double-buffered 4-plane staging) ----------------
// C(M,N) f32 [+Add] = A @ Bt^T.  A:(M,lda) fp16, Bt:(N,lda) fp16 pre-transposed.
// SPLIT=1: [hi K|lo K] (lda=2K); per 32-k-slice stage Ah/Al/Bh/Bl, 3 MFMA terms.
// SPLIT=0: lda=K, BK=64 (two 32-slices per step, 2 MFMA per fragment).
// Double-buffered: STAGE(next) issued BEFORE compute; one __syncthreads per step
// (its vmcnt(0) drain covers the prefetch, whose latency hid under the MFMAs).
template <int BN, int SPLIT, int ADD, int NTAIL>
__global__ void __launch_bounds__(256) gemm_h(
    const unsigned short* __restrict__ A, const unsigned short* __restrict__ Bt,
    float* __restrict__ C, const float* __restrict__ Add,
    int M, int N, int K, int ldc, int gx, int gy,
    long long sA, long long sB, int zdiv, long long sC1, long long sC2) {
  constexpr int FN = (BN == 128) ? 4 : 2;
  constexpr int APL = 128 * 32;            // A plane (shorts)
  constexpr int BPL = BN * 32;             // B plane (shorts)
  constexpr int BUF = 2 * APL + 2 * BPL;   // Ah|Al|Bh|Bl
  __shared__ __align__(16) unsigned short lds[2][BUF];
  int tot = gridDim.x;
  int lin = blockIdx.x;
  if ((tot & 7) == 0) lin = (lin & 7) * (tot >> 3) + (lin >> 3);  // XCD chunking
  int pz = lin / (gx * gy);
  int r2 = lin - pz * (gx * gy);
  const int m0 = (r2 % gx) * 128, n0 = (r2 / gx) * BN;
  A += (long long)pz * sA;
  Bt += (long long)pz * sB;
  const long long co = (long long)(pz / zdiv) * sC1 + (long long)(pz % zdiv) * sC2;
  const int lda = SPLIT ? 2 * K : K;
  const int NS = SPLIT ? K / 32 : K / 64;
  const int tid = threadIdx.x;
  const int lane = tid & 63, wave = tid >> 6;
  const int wm = (BN == 128) ? (wave >> 1) : (wave & 1);
  const int wn = (BN == 128) ? (wave & 1) : (wave >> 1);
  const int srow = tid >> 2, scol = (tid & 3) * 8;
  const unsigned short* Ar = A + (long long)(m0 + srow) * lda + scol;
  int br0 = n0 + srow;
  if (NTAIL) br0 = min(br0, N - 1);
  const unsigned short* Br = Bt + (long long)br0 * lda + scol;
  int br1 = n0 + srow + 64;
  if (NTAIL) br1 = min(br1, N - 1);
  const unsigned short* Br2 = Bt + (long long)br1 * lda + scol;

  auto STAGE = [&](int buf, int s) {
    const int kh = SPLIT ? s * 32 : s * 64;
    const int kl = SPLIT ? K + s * 32 : s * 64 + 32;
    unsigned short* L = lds[buf];
    gload16(Ar + kh, &L[wave * 512]);
    gload16(Ar + (long long)64 * lda + kh, &L[2048 + wave * 512]);
    gload16(Ar + kl, &L[APL + wave * 512]);
    gload16(Ar + (long long)64 * lda + kl, &L[APL + 2048 + wave * 512]);
    gload16(Br + kh, &L[2 * APL + wave * 512]);
    gload16(Br + kl, &L[2 * APL + BPL + wave * 512]);
    if (BN == 128) {
      gload16(Br2 + kh, &L[2 * APL + 2048 + wave * 512]);
      gload16(Br2 + kl, &L[2 * APL + BPL + 2048 + wave * 512]);
    }
  };

  f32x4 acc[4][FN];
  #pragma unroll
  for (int m = 0; m < 4; ++m)
    #pragma unroll
    for (int n = 0; n < FN; ++n) acc[m][n] = (f32x4){0.f, 0.f, 0.f, 0.f};

  STAGE(0, 0);
  __syncthreads();
  int cur = 0;
  for (int s = 0; s < NS; ++s) {
    if (s + 1 < NS) STAGE(cur ^ 1, s + 1);     // prefetch next (latency hides under MFMA)
    const unsigned short* L = lds[cur];
    half8 bfh[FN], bfl[FN];
    #pragma unroll
    for (int n = 0; n < FN; ++n) {
      int bo = (wn * (FN * 16) + n * 16 + (lane & 15)) * 32 + (lane >> 4) * 8;
      bfh[n] = *(const half8*)&L[2 * APL + bo];
      bfl[n] = *(const half8*)&L[2 * APL + BPL + bo];
    }
    __builtin_amdgcn_s_setprio(1);
    #pragma unroll
    for (int m = 0; m < 4; ++m) {
      int ao = (wm * 64 + m * 16 + (lane & 15)) * 32 + (lane >> 4) * 8;
      half8 afh = *(const half8*)&L[ao];
      half8 afl = *(const half8*)&L[APL + ao];
      #pragma unroll
      for (int n = 0; n < FN; ++n) {
        acc[m][n] = __builtin_amdgcn_mfma_f32_16x16x32_f16(afh, bfh[n], acc[m][n], 0, 0, 0);
        if (SPLIT) {
          acc[m][n] = __builtin_amdgcn_mfma_f32_16x16x32_f16(afl, bfh[n], acc[m][n], 0, 0, 0);
          acc[m][n] = __builtin_amdgcn_mfma_f32_16x16x32_f16(afh, bfl[n], acc[m][n], 0, 0, 0);
        } else {
          acc[m][n] = __builtin_amdgcn_mfma_f32_16x16x32_f16(afl, bfl[n], acc[m][n], 0, 0, 0);
        }
      }
    }
    __builtin_amdgcn_s_setprio(0);
    __syncthreads();   // vmcnt(0): prefetch landed; lgkm: reads done; barrier
    cur ^= 1;
  }
  #pragma unroll
  for (int m = 0; m < 4; ++m)
    #pragma unroll
    for (int n = 0; n < FN; ++n) {
      int col = n0 + wn * (FN * 16) + n * 16 + (lane & 15);
      if (!NTAIL || col < N) {
        #pragma unroll
        for (int j = 0; j < 4; ++j) {
          long long row = m0 + wm * 64 + m * 16 + (lane >> 4) * 4 + j;
          long long o = co + row * ldc + col;
          float v = acc[m][n][j];
          if (ADD) v += Add[o];
          C[o] = v;
        }
      }
    }
}

// ---------------- host launch ----------------

extern "C" void kernel_launch(void* const* d_in, const int* in_sizes, int n_in,
                              void* d_out, int out_size, void* d_ws, size_t ws_size,
                              hipStream_t stream) {
  (void)in_sizes; (void)n_in; (void)out_size; (void)ws_size;
  const int*   idx   = (const int*)d_in[0];
  const float* wte   = (const float*)d_in[1];
  const float* wqkv  = (const float*)d_in[2];
  const float* qnw   = (const float*)d_in[3];
  const float* knw   = (const float*)d_in[4];
  const float* oproj = (const float*)d_in[5];
  const float* ffnw  = (const float*)d_in[6];
  const float* gatew = (const float*)d_in[7];
  const float* w13   = (const float*)d_in[8];
  const float* w2p   = (const float*)d_in[9];
  const float* lnf   = (const float*)d_in[10];
  float* out = (float*)d_out;

  char* base = (char*)d_ws;
  size_t off = 0;
  auto alloc = [&](size_t bytes) -> char* {
    off = (off + 255) & ~(size_t)255;
    char* p = base + off; off += bytes; return p;
  };
  float* x     = (float*)alloc((size_t)Ntok * 768 * 4);
  float* qkv   = (float*)alloc((size_t)Ntok * 2304 * 4);
  float* hbuf  = (float*)alloc((size_t)Ntok * 768 * 4);
  float* ffn   = (float*)alloc((size_t)Ntok * 768 * 4);
  unsigned short* x16   = (unsigned short*)alloc((size_t)Ntok * 1536 * 2);
  unsigned short* yfl16 = (unsigned short*)alloc((size_t)Ntok * 1536 * 2);
  unsigned short* qr16  = (unsigned short*)alloc((size_t)24 * 1024 * 128 * 2);
  unsigned short* kr16  = (unsigned short*)alloc((size_t)24 * 1024 * 128 * 2);
  unsigned short* vr16  = (unsigned short*)alloc((size_t)24 * 64 * 2048 * 2);
  unsigned short* xb16  = (unsigned short*)alloc((size_t)Ec * CAPPc * 1536 * 2);
  unsigned short* wo16  = (unsigned short*)alloc((size_t)768 * 1536 * 2);
  unsigned short* xf16  = (unsigned short*)alloc((size_t)Ntok * 768 * 2);
  char* spb = alloc((size_t)24 * 1024 * 1024 * 4);           // scratch region
  float* gu   = (float*)spb;                                 // [0, 50.3M)
  float* yexp = (float*)spb;                                 // [0, 9.4M) over dead gu
  unsigned short* act16 = (unsigned short*)(spb + 50331648); // [50.3M, 75.5M)
  unsigned short* wq16  = (unsigned short*)(spb + 75497472); // [75.5M, 82.6M)
  unsigned short* w13_16 = (unsigned short*)alloc((size_t)Ec * 4096 * 1536 * 2); // 100.66MB
  unsigned short* wt16   = w13_16;                           // alias (used after)
  unsigned short* w2_16  = (unsigned short*)alloc((size_t)Ec * 768 * 4096 * 2);  // 50.3MB
  int* top    = (int*)alloc(Ntok * 4);
  int* rankb  = (int*)alloc(Ntok * 4);
  int* cnt    = (int*)alloc(Lc * Ec * 4);
  float* psum = (float*)alloc(Lc * Ec * 4);
  float* z2   = (float*)alloc(Lc * 4);

  zero_small<<<1, 64, 0, stream>>>(psum, z2);
  embed_k<<<Ntok, 192, 0, stream>>>(idx, wte, x, x16);

  for (int l = 0; l < Lc; ++l) {
    split2_wT<1><<<dim3(72, 24, 1), 256, 0, stream>>>(wqkv + (size_t)l * 768 * 2304, wq16,
                                                      768, 2304, 0, 0);
    split2_wT<1><<<dim3(24, 24, 1), 256, 0, stream>>>(oproj + (size_t)l * 768 * 768, wo16,
                                                      768, 768, 0, 0);
    if (l == 0) {
      split2_wT<1><<<dim3(128, 24, 8), 256, 0, stream>>>(w13, w13_16,
          768, 4096, (long long)768 * 4096, (long long)4096 * 1536);
      split2_wT<1><<<dim3(24, 64, 8), 256, 0, stream>>>(w2p, w2_16,
          2048, 768, (long long)2048 * 768, (long long)768 * 4096);
    } else {
      split2_wT<0><<<dim3(128, 24, 8), 256, 0, stream>>>(w13 + (size_t)Ec * 768 * 4096, w13_16,
          768, 4096, (long long)768 * 4096, (long long)4096 * 768);
      split2_wT<0><<<dim3(24, 64, 8), 256, 0, stream>>>(w2p + (size_t)Ec * 2048 * 768, w2_16,
          2048, 768, (long long)2048 * 768, (long long)768 * 2048);
    }
    // qkv = x @ wqkv[l]
    gemm_h<128, 1, 0, 0><<<288, 256, 0, stream>>>(
        x16, wq16, qkv, nullptr, 2048, 2304, 768, 2304, 16, 18, 0, 0, 1, 0, 0);
    // fused q/k rmsnorm + rope + V transpose
    qk_rope<<<Ntok, 256, 0, stream>>>(qkv, qnw + l * 768, knw + l * 768, qr16, kr16, vr16);
    // fused attention -> yfl16 (split-fp16)
    flash_attn<<<384, 256, 0, stream>>>(qr16, kr16, vr16, yfl16);
    // h = x + y @ o_proj[l]
    gemm_h<64, 1, 1, 0><<<192, 256, 0, stream>>>(
        yfl16, wo16, hbuf, x, 2048, 768, 768, 768, 16, 12, 0, 0, 1, 0, 0);
    rmsnorm_k<<<Ntok, 256, 0, stream>>>(hbuf, 768, ffn, 768, ffnw + l * 768);
    gate_k<<<Ntok / 256, 256, 0, stream>>>(ffn, gatew + (size_t)l * 768 * 8, top,
                                           psum + l * 8, z2 + l);
    route_scan<<<1, 64, 0, stream>>>(top, rankb, cnt + l * 8);
    if (l == 0) {
      scatter_xb<1><<<Ntok, 192, 0, stream>>>(ffn, top, rankb, xb16);
      gemm_h<128, 1, 0, 0><<<768, 256, 0, stream>>>(
          xb16, w13_16, gu, nullptr, 384, 4096, 768, 4096, 3, 32,
          (long long)384 * 1536, (long long)4096 * 1536, 1, (long long)384 * 4096, 0);
      silu_k<1><<<(Ec * CAPPc * Hc) / 256, 256, 0, stream>>>(gu, act16);
      gemm_h<64, 1, 0, 0><<<288, 256, 0, stream>>>(
          act16, w2_16, yexp, nullptr, 384, 768, 2048, 768, 3, 12,
          (long long)384 * 4096, (long long)768 * 4096, 1, (long long)384 * 768, 0);
    } else {
      scatter_xb<0><<<Ntok, 192, 0, stream>>>(ffn, top, rankb, xb16);
      gemm_h<128, 0, 0, 0><<<768, 256, 0, stream>>>(
          xb16, w13_16, gu, nullptr, 384, 4096, 768, 4096, 3, 32,
          (long long)384 * 768, (long long)4096 * 768, 1, (long long)384 * 4096, 0);
      silu_k<0><<<(Ec * CAPPc * Hc) / 256, 256, 0, stream>>>(gu, act16);
      gemm_h<64, 0, 0, 0><<<288, 256, 0, stream>>>(
          act16, w2_16, yexp, nullptr, 384, 768, 2048, 768, 3, 12,
          (long long)384 * 2048, (long long)768 * 2048, 1, (long long)384 * 768, 0);
    }
    gather_add<<<Ntok, 192, 0, stream>>>(hbuf, yexp, top, rankb, x, x16);
  }

  rmsnorm_h<<<Ntok, 256, 0, stream>>>(x, xf16, lnf);
  f2h4<<<(int)(((long long)Vc * 768 / 4 + 255) / 256), 256, 0, stream>>>(
      wte, wt16, (long long)Vc * 768 / 4);
  // logits = xf @ wte^T  (single fp16, BK=64 dbuf, N tail handled)
  gemm_h<128, 0, 0, 1><<<6288, 256, 0, stream>>>(
      xf16, wt16, out, nullptr, 2048, Vc, 768, Vc, 16, 393, 0, 0, 1, 0, 0);
  aux_fin<<<1, 64, 0, stream>>>(psum, cnt, z2, out + LOGITS_N);
}

// Round 7
// 1285.731 us; speedup vs baseline: 1.3370x; 1.0389x over previous
//
// LunarisCodex MoE-GPT forward, MI355X/gfx950. Round 7: TRUE pipelined GEMM —
// raw s_barrier + counted vmcnt(8/6) (T3/T4), no vmcnt(0) drain in steady state.
// R6's __syncthreads-dbuf drained the prefetch at every barrier (m233 trap).
#include <hip/hip_runtime.h>

typedef __attribute__((ext_vector_type(8))) _Float16 half8;
typedef __attribute__((ext_vector_type(4))) float f32x4;

constexpr int Bc = 2, Tc = 1024, Dc = 768, NHc = 12, HDc = 64;
constexpr int Vc = 50257, Lc = 2, Ec = 8, Hc = 2048;
constexpr int Ntok = Bc * Tc;            // 2048
constexpr int CAPc = 320, CAPPc = 384;   // capacity, padded rows per expert
constexpr long long LOGITS_N = (long long)Bc * Tc * Vc;  // 102926336

typedef const __attribute__((address_space(1))) unsigned int* gas_t;
typedef __attribute__((address_space(3))) unsigned int* las_t;
__device__ __forceinline__ void gload16(const void* g, void* l) {
  __builtin_amdgcn_global_load_lds((gas_t)g, (las_t)l, 16, 0, 0);
}

__device__ __forceinline__ void splitf16(float a, unsigned short& h, unsigned short& l) {
  _Float16 hh = (_Float16)a;                       // RNE
  _Float16 ll = (_Float16)(a - (float)hh);
  h = __builtin_bit_cast(unsigned short, hh);
  l = __builtin_bit_cast(unsigned short, ll);
}
__device__ __forceinline__ unsigned short f16o(float a) {
  _Float16 hh = (_Float16)a;
  return __builtin_bit_cast(unsigned short, hh);
}

// ---------------- small kernels ----------------

__global__ void zero_small(float* psum, float* z2) {
  int t = threadIdx.x;
  if (t < Lc * Ec) psum[t] = 0.f;
  if (t < Lc) z2[t] = 0.f;
}

// embed: x (f32) + x16 (split-fp16 [hi768|lo768])
__global__ void embed_k(const int* __restrict__ idx, const float* __restrict__ wte,
                        float* __restrict__ x, unsigned short* __restrict__ x16) {
  int n = blockIdx.x;
  long long v = idx[n];
  const float4* src = (const float4*)(wte + v * 768);
  float4* dst = (float4*)(x + (long long)n * 768);
  int t = threadIdx.x;
  if (t < 192) {
    float4 val = src[t];
    dst[t] = val;
    ushort4 h, l;
    splitf16(val.x, h.x, l.x); splitf16(val.y, h.y, l.y);
    splitf16(val.z, h.z, l.z); splitf16(val.w, h.w, l.w);
    unsigned short* d = x16 + (long long)n * 1536 + t * 4;
    *(ushort4*)d = h;
    *(ushort4*)(d + 768) = l;
  }
}

// f32 -> fp16 single (for wte)
__global__ void f2h4(const float* __restrict__ in, unsigned short* __restrict__ out,
                     long long n4) {
  long long i = (long long)blockIdx.x * 256 + threadIdx.x;
  if (i >= n4) return;
  float4 v = ((const float4*)in)[i];
  ushort4 o;
  o.x = f16o(v.x); o.y = f16o(v.y); o.z = f16o(v.z); o.w = f16o(v.w);
  ((ushort4*)out)[i] = o;
}

// f32 weights (K,N) -> fp16 transposed. SP=1: (N,2K) [hi|lo]; SP=0: (N,K) hi only.
template <int SP>
__global__ void __launch_bounds__(256) split2_wT(const float* __restrict__ src,
    unsigned short* __restrict__ dst, int K, int N, long long sS, long long sD) {
  __shared__ float t[32][33];
  int z = blockIdx.z;
  src += (long long)z * sS;
  dst += (long long)z * sD;
  int n0 = blockIdx.x * 32, k0 = blockIdx.y * 32;
  int tid = threadIdx.x;
  int r = tid >> 3, c4 = (tid & 7) * 4;
  float4 v = *(const float4*)(src + (long long)(k0 + r) * N + n0 + c4);
  t[r][c4 + 0] = v.x; t[r][c4 + 1] = v.y; t[r][c4 + 2] = v.z; t[r][c4 + 3] = v.w;
  __syncthreads();
  int n = tid >> 3, kq = (tid & 7) * 4;
  ushort4 h, l;
  splitf16(t[kq + 0][n], h.x, l.x);
  splitf16(t[kq + 1][n], h.y, l.y);
  splitf16(t[kq + 2][n], h.z, l.z);
  splitf16(t[kq + 3][n], h.w, l.w);
  const int lda = SP ? 2 * K : K;
  unsigned short* d = dst + (long long)(n0 + n) * lda + k0 + kq;
  *(ushort4*)d = h;
  if (SP) *(ushort4*)(d + K) = l;
}

// rmsnorm over 768 cols; strided in/out, f32 out
__global__ void __launch_bounds__(256) rmsnorm_k(const float* in, int istride,
                                                 float* outp, int ostride,
                                                 const float* w) {
  long long n = blockIdx.x;
  const float* xr = in + n * istride;
  float* yr = outp + n * ostride;
  int tid = threadIdx.x;
  float s = 0.f;
  for (int i = tid; i < 768; i += 256) { float v = xr[i]; s += v * v; }
  #pragma unroll
  for (int o = 32; o; o >>= 1) s += __shfl_down(s, o);
  __shared__ float red[4];
  __shared__ float bs;
  if ((tid & 63) == 0) red[tid >> 6] = s;
  __syncthreads();
  if (tid == 0) bs = rsqrtf((red[0] + red[1] + red[2] + red[3]) / 768.0f + 1e-5f);
  __syncthreads();
  float sc = bs;
  for (int i = tid; i < 768; i += 256) yr[i] = xr[i] * sc * w[i];
}

// rmsnorm -> fp16 single output (final ln before logits)
__global__ void __launch_bounds__(256) rmsnorm_h(const float* in,
                                                 unsigned short* outp, const float* w) {
  long long n = blockIdx.x;
  const float* xr = in + n * 768;
  unsigned short* yr = outp + n * 768;
  int tid = threadIdx.x;
  float s = 0.f;
  for (int i = tid; i < 768; i += 256) { float v = xr[i]; s += v * v; }
  #pragma unroll
  for (int o = 32; o; o >>= 1) s += __shfl_down(s, o);
  __shared__ float red[4];
  __shared__ float bs;
  if ((tid & 63) == 0) red[tid >> 6] = s;
  __syncthreads();
  if (tid == 0) bs = rsqrtf((red[0] + red[1] + red[2] + red[3]) / 768.0f + 1e-5f);
  __syncthreads();
  float sc = bs;
  for (int i = tid; i < 768; i += 256) yr[i] = f16o(xr[i] * sc * w[i]);
}

// fused q/k rmsnorm + RoPE + V transpose. One block per token.
__global__ void __launch_bounds__(256) qk_rope(const float* __restrict__ qkv,
    const float* __restrict__ qnw, const float* __restrict__ knw,
    unsigned short* __restrict__ qr, unsigned short* __restrict__ kr,
    unsigned short* __restrict__ vr) {
  int n = blockIdx.x;
  int t = n & 1023, b = n >> 10;
  const float* row = qkv + (long long)n * 2304;
  int tid = threadIdx.x;
  float sq = 0.f, sk = 0.f;
  for (int i = tid; i < 768; i += 256) {
    float q = row[i]; sq += q * q;
    float k = row[768 + i]; sk += k * k;
  }
  #pragma unroll
  for (int o = 32; o; o >>= 1) { sq += __shfl_down(sq, o); sk += __shfl_down(sk, o); }
  __shared__ float redq[4], redk[4];
  __shared__ float bq, bk;
  if ((tid & 63) == 0) { redq[tid >> 6] = sq; redk[tid >> 6] = sk; }
  __syncthreads();
  if (tid == 0) {
    bq = rsqrtf((redq[0] + redq[1] + redq[2] + redq[3]) / 768.0f + 1e-5f);
    bk = rsqrtf((redk[0] + redk[1] + redk[2] + redk[3]) / 768.0f + 1e-5f);
  }
  __syncthreads();
  float nq = bq, nk = bk;
  for (int i = tid; i < 384; i += 256) {
    int hh = i >> 5, j = i & 31;
    int c = hh * 64 + 2 * j;
    float ang = (float)t * powf(10000.0f, -((float)j * (1.0f / 32.0f)));
    float cs = cosf(ang), sn = sinf(ang);
    int z = b * 12 + hh;
    long long qb = ((long long)z * 1024 + t) * 128 + 2 * j;
    unsigned short h0, l0, h1, l1;
    float q0 = row[c] * nq * qnw[c], q1 = row[c + 1] * nq * qnw[c + 1];
    splitf16(q0 * cs - q1 * sn, h0, l0);
    splitf16(q0 * sn + q1 * cs, h1, l1);
    *(unsigned int*)&qr[qb] = (unsigned)h0 | ((unsigned)h1 << 16);
    *(unsigned int*)&qr[qb + 64] = (unsigned)l0 | ((unsigned)l1 << 16);
    float k0 = row[768 + c] * nk * knw[c], k1 = row[768 + c + 1] * nk * knw[c + 1];
    splitf16(k0 * cs - k1 * sn, h0, l0);
    splitf16(k0 * sn + k1 * cs, h1, l1);
    *(unsigned int*)&kr[qb] = (unsigned)h0 | ((unsigned)h1 << 16);
    *(unsigned int*)&kr[qb + 64] = (unsigned)l0 | ((unsigned)l1 << 16);
    splitf16(row[1536 + c], h0, l0);
    splitf16(row[1536 + c + 1], h1, l1);
    long long vb = ((long long)z * 64 + 2 * j) * 2048 + t;
    vr[vb] = h0; vr[vb + 1024] = l0;
    vr[vb + 2048] = h1; vr[vb + 3072] = l1;
  }
}

// ---------------- fused flash attention ----------------
__global__ void __launch_bounds__(256) flash_attn(
    const unsigned short* __restrict__ qr, const unsigned short* __restrict__ kr,
    const unsigned short* __restrict__ vr, unsigned short* __restrict__ yout) {
  __shared__ __align__(16) unsigned short Ph[4][16][72];
  __shared__ __align__(16) unsigned short Pl[4][16][72];
  int bid = blockIdx.x;
  int z = bid >> 4;
  int qt = 15 - (bid & 15);          // heavy tiles first (load balance)
  int b = z / 12, h = z % 12;
  int q0 = qt * 64;
  int wave = threadIdx.x >> 6, lane = threadIdx.x & 63;
  int lr = lane & 15, lg = lane >> 4;
  int qw = q0 + wave * 16;           // this wave's 16 q rows
  half8 af[2][2];
  const unsigned short* qbase = qr + ((long long)z * 1024 + qw + lr) * 128;
  #pragma unroll
  for (int ks = 0; ks < 2; ++ks)
    #pragma unroll
    for (int p = 0; p < 2; ++p)
      af[ks][p] = *(const half8*)(qbase + p * 64 + ks * 32 + lg * 8);
  f32x4 accy[4];
  #pragma unroll
  for (int df = 0; df < 4; ++df) accy[df] = (f32x4){0.f, 0.f, 0.f, 0.f};
  float mrun[4] = {-3.4e38f, -3.4e38f, -3.4e38f, -3.4e38f};
  float srun[4] = {0.f, 0.f, 0.f, 0.f};
  for (int kt = 0; kt <= qt; ++kt) {
    int kv0 = kt * 64;
    f32x4 s[4];
    #pragma unroll
    for (int nf = 0; nf < 4; ++nf) s[nf] = (f32x4){0.f, 0.f, 0.f, 0.f};
    const unsigned short* kbase = kr + ((long long)z * 1024 + kv0 + lr) * 128;
    #pragma unroll
    for (int nf = 0; nf < 4; ++nf) {
      const unsigned short* kb = kbase + nf * 16 * 128;
      #pragma unroll
      for (int ks = 0; ks < 2; ++ks) {
        half8 bh = *(const half8*)(kb + ks * 32 + lg * 8);
        half8 bl = *(const half8*)(kb + 64 + ks * 32 + lg * 8);
        s[nf] = __builtin_amdgcn_mfma_f32_16x16x32_f16(af[ks][0], bh, s[nf], 0, 0, 0);
        s[nf] = __builtin_amdgcn_mfma_f32_16x16x32_f16(af[ks][1], bh, s[nf], 0, 0, 0);
        s[nf] = __builtin_amdgcn_mfma_f32_16x16x32_f16(af[ks][0], bl, s[nf], 0, 0, 0);
      }
    }
    bool diag = (kt == qt);
    #pragma unroll
    for (int nf = 0; nf < 4; ++nf)
      #pragma unroll
      for (int j = 0; j < 4; ++j) {
        float v = s[nf][j] * 0.125f;
        if (diag && (nf * 16 + lr > wave * 16 + lg * 4 + j)) v = -1e30f;
        s[nf][j] = v;
      }
    #pragma unroll
    for (int j = 0; j < 4; ++j) {
      float tm = fmaxf(fmaxf(s[0][j], s[1][j]), fmaxf(s[2][j], s[3][j]));
      #pragma unroll
      for (int o = 1; o < 16; o <<= 1) tm = fmaxf(tm, __shfl_xor(tm, o));
      float mnew = fmaxf(mrun[j], tm);
      float sc = expf(mrun[j] - mnew);
      float ts = 0.f;
      #pragma unroll
      for (int nf = 0; nf < 4; ++nf) {
        float p = expf(s[nf][j] - mnew);
        ts += p;
        unsigned short ph, pl;
        splitf16(p, ph, pl);
        Ph[wave][lg * 4 + j][nf * 16 + lr] = ph;
        Pl[wave][lg * 4 + j][nf * 16 + lr] = pl;
      }
      #pragma unroll
      for (int o = 1; o < 16; o <<= 1) ts += __shfl_xor(ts, o);
      srun[j] = srun[j] * sc + ts;
      mrun[j] = mnew;
      #pragma unroll
      for (int df = 0; df < 4; ++df) accy[df][j] *= sc;
    }
    #pragma unroll
    for (int ks2 = 0; ks2 < 2; ++ks2) {
      half8 aph = *(const half8*)&Ph[wave][lr][ks2 * 32 + lg * 8];
      half8 apl = *(const half8*)&Pl[wave][lr][ks2 * 32 + lg * 8];
      #pragma unroll
      for (int df = 0; df < 4; ++df) {
        const unsigned short* vb =
            vr + ((long long)z * 64 + df * 16 + lr) * 2048 + kv0 + ks2 * 32 + lg * 8;
        half8 bvh = *(const half8*)vb;
        half8 bvl = *(const half8*)(vb + 1024);
        accy[df] = __builtin_amdgcn_mfma_f32_16x16x32_f16(aph, bvh, accy[df], 0, 0, 0);
        accy[df] = __builtin_amdgcn_mfma_f32_16x16x32_f16(apl, bvh, accy[df], 0, 0, 0);
        accy[df] = __builtin_amdgcn_mfma_f32_16x16x32_f16(aph, bvl, accy[df], 0, 0, 0);
      }
    }
  }
  float inv[4];
  #pragma unroll
  for (int j = 0; j < 4; ++j) inv[j] = 1.0f / srun[j];
  #pragma unroll
  for (int df = 0; df < 4; ++df)
    #pragma unroll
    for (int j = 0; j < 4; ++j) {
      long long tok = (long long)b * 1024 + qw + lg * 4 + j;
      int col = h * 64 + df * 16 + lr;
      unsigned short hh, ll;
      splitf16(accy[df][j] * inv[j], hh, ll);
      yout[tok * 1536 + col] = hh;
      yout[tok * 1536 + 768 + col] = ll;
    }
}

// gate: logits(f32), softmax probs, argmax (first-max), aux accumulators
__global__ void __launch_bounds__(256) gate_k(const float* __restrict__ xin,
    const float* __restrict__ gw, int* __restrict__ top,
    float* __restrict__ psum, float* __restrict__ z2) {
  __shared__ float gws[768 * 8];
  __shared__ float pacc[8];
  __shared__ float zacc;
  int tid = threadIdx.x;
  for (int i = tid; i < 768 * 8 / 4; i += 256) ((float4*)gws)[i] = ((const float4*)gw)[i];
  if (tid < 8) pacc[tid] = 0.f;
  if (tid == 0) zacc = 0.f;
  __syncthreads();
  int n = blockIdx.x * 256 + tid;
  const float4* xr4 = (const float4*)(xin + (long long)n * 768);
  float l[8] = {0, 0, 0, 0, 0, 0, 0, 0};
  for (int d4 = 0; d4 < 192; ++d4) {
    float4 xv = xr4[d4];
    const float* g = &gws[d4 * 32];
    #pragma unroll
    for (int e = 0; e < 8; ++e)
      l[e] += xv.x * g[e] + xv.y * g[8 + e] + xv.z * g[16 + e] + xv.w * g[24 + e];
  }
  float mx = l[0]; int bi = 0;
  #pragma unroll
  for (int e = 1; e < 8; ++e) if (l[e] > mx) { mx = l[e]; bi = e; }  // first-max
  float p[8]; float se = 0.f;
  #pragma unroll
  for (int e = 0; e < 8; ++e) { p[e] = expf(l[e] - mx); se += p[e]; }
  float z = mx + logf(se);
  top[n] = bi;
  #pragma unroll
  for (int e = 0; e < 8; ++e) atomicAdd(&pacc[e], p[e] / se);
  atomicAdd(&zacc, z * z);
  __syncthreads();
  if (tid < 8) atomicAdd(&psum[tid], pacc[tid]);
  if (tid == 0) atomicAdd(z2, zacc);
}

// single-wave rank scan (matches stable argsort arrival order)
__global__ void route_scan(const int* __restrict__ top, int* __restrict__ rank,
                           int* __restrict__ cnt) {
  int lane = threadIdx.x;
  int c[8] = {0, 0, 0, 0, 0, 0, 0, 0};
  unsigned long long below = (1ull << lane) - 1ull;
  for (int s = 0; s < Ntok / 64; ++s) {
    int n = s * 64 + lane;
    int e = top[n];
    int r = 0;
    #pragma unroll
    for (int q = 0; q < 8; ++q) {
      unsigned long long m = __ballot(e == q);
      if (e == q) r = c[q] + __popcll(m & below);
      c[q] += __popcll(m);
    }
    rank[n] = r;
  }
  #pragma unroll
  for (int q = 0; q < 8; ++q) if (lane == q) cnt[q] = c[q];
}

// ffn f32 -> xb16. SP=1: (row,1536=[hi|lo]); SP=0: (row,768) hi only.
template <int SP>
__global__ void scatter_xb(const float* __restrict__ xin, const int* __restrict__ top,
                           const int* __restrict__ rank, unsigned short* __restrict__ xb) {
  int n = blockIdx.x;
  int r = rank[n];
  if (r >= CAPc) return;
  int e = top[n];
  int t = threadIdx.x;
  if (t >= 192) return;
  float4 v = ((const float4*)(xin + (long long)n * 768))[t];
  ushort4 h, l;
  splitf16(v.x, h.x, l.x); splitf16(v.y, h.y, l.y);
  splitf16(v.z, h.z, l.z); splitf16(v.w, h.w, l.w);
  const int lda = SP ? 1536 : 768;
  unsigned short* dst = xb + ((long long)e * CAPPc + r) * lda + t * 4;
  *(ushort4*)dst = h;
  if (SP) *(ushort4*)(dst + 768) = l;
}

// gu f32 (rows,4096=[g|u]) -> act16. SP=1: (rows,4096=[hi2048|lo2048]); SP=0: (rows,2048).
template <int SP>
__global__ void __launch_bounds__(256) silu_k(const float* __restrict__ gu,
                                              unsigned short* __restrict__ act) {
  long long i = (long long)blockIdx.x * 256 + threadIdx.x;  // < E*CAPP*H
  long long row = i >> 11;
  int h = (int)(i & 2047);
  float g = gu[row * 4096 + h];
  float u = gu[row * 4096 + 2048 + h];
  float a = g / (1.f + expf(-g)) * u;
  if (SP) {
    unsigned short hh, ll;
    splitf16(a, hh, ll);
    act[row * 4096 + h] = hh;
    act[row * 4096 + 2048 + h] = ll;
  } else {
    act[row * 2048 + h] = f16o(a);
  }
}

// h + expert-out -> x (f32) AND x16 (split-fp16) for next layer
__global__ void gather_add(const float* __restrict__ h, const float* __restrict__ yexp,
                           const int* __restrict__ top, const int* __restrict__ rank,
                           float* __restrict__ xo, unsigned short* __restrict__ x16) {
  int n = blockIdx.x;
  int r = rank[n], e = top[n];
  bool kept = r < CAPc;
  int rc = kept ? r : (CAPc - 1);
  const float4* hs = (const float4*)(h + (long long)n * 768);
  const float4* ys = (const float4*)(yexp + ((long long)e * CAPPc + rc) * 768);
  float4* dst = (float4*)(xo + (long long)n * 768);
  int t = threadIdx.x;
  if (t < 192) {
    float4 v = hs[t];
    if (kept) { float4 y = ys[t]; v.x += y.x; v.y += y.y; v.z += y.z; v.w += y.w; }
    dst[t] = v;
    ushort4 hh, ll;
    splitf16(v.x, hh.x, ll.x); splitf16(v.y, hh.y, ll.y);
    splitf16(v.z, hh.z, ll.z); splitf16(v.w, hh.w, ll.w);
    unsigned short* d = x16 + (long long)n * 1536 + t * 4;
    *(ushort4*)d = hh;
    *(ushort4*)(d + 768) = ll;
  }
}

__global__ void aux_fin(const float* __restrict__ psum, const int* __restrict__ cnt,
                        const float* __restrict__ z2, float* __restrict__ outp) {
  if (threadIdx.x == 0) {
    float aux = 0.f;
    for (int l = 0; l < Lc; ++l) {
      float bl = 0.f;
      for (int e = 0; e < 8; ++e)
        bl += (psum[l * 8 + e] * (1.0f / 2048.0f)) * ((float)cnt[l * 8 + e] * (1.0f / 2048.0f));
      aux += bl * (0.01f * 8.0f) + (z2[l] * (1.0f / 2048.0f)) * 0.001f;
    }
    outp[0] = aux;
  }
}

// ---------------- fp16 MFMA GEMM (true pipelined dbuf: counted vmcnt) ----------
// C(M,N) f32 [+Add] = A @ Bt^T. SPLIT=1: [hi K|lo K] (lda=2K), 3 MFMA terms per
// 32-k-slice (4 planes). SPLIT=0: lda=K, BK=64 (2 planes).
// Pipeline per iter: STAGE(next) -> vmcnt(LPS) [prev stage landed; next stays in
// flight] -> s_barrier -> ds_read+MFMA -> s_barrier. No vmcnt(0) in steady state.
template <int BN, int SPLIT, int ADD, int NTAIL>
__global__ void __launch_bounds__(256) gemm_h(
    const unsigned short* __restrict__ A, const unsigned short* __restrict__ Bt,
    float* __restrict__ C, const float* __restrict__ Add,
    int M, int N, int K, int ldc, int gx, int gy,
    long long sA, long long sB, int zdiv, long long sC1, long long sC2) {
  constexpr int FN = (BN == 128) ? 4 : 2;
  constexpr int APL = 128 * 32;            // A plane (shorts)
  constexpr int BPL = BN * 32;             // B plane (shorts)
  constexpr int BUF = 2 * APL + 2 * BPL;   // Ah|Al|Bh|Bl
  __shared__ __align__(16) unsigned short lds[2][BUF];
  int tot = gridDim.x;
  int lin = blockIdx.x;
  if ((tot & 7) == 0) lin = (lin & 7) * (tot >> 3) + (lin >> 3);  // XCD chunking
  int pz = lin / (gx * gy);
  int r2 = lin - pz * (gx * gy);
  const int m0 = (r2 % gx) * 128, n0 = (r2 / gx) * BN;
  A += (long long)pz * sA;
  Bt += (long long)pz * sB;
  const long long co = (long long)(pz / zdiv) * sC1 + (long long)(pz % zdiv) * sC2;
  const int lda = SPLIT ? 2 * K : K;
  const int NS = SPLIT ? K / 32 : K / 64;
  const int tid = threadIdx.x;
  const int lane = tid & 63, wave = tid >> 6;
  const int wm = (BN == 128) ? (wave >> 1) : (wave & 1);
  const int wn = (BN == 128) ? (wave & 1) : (wave >> 1);
  const int srow = tid >> 2, scol = (tid & 3) * 8;
  const unsigned short* Ar = A + (long long)(m0 + srow) * lda + scol;
  int br0 = n0 + srow;
  if (NTAIL) br0 = min(br0, N - 1);
  const unsigned short* Br = Bt + (long long)br0 * lda + scol;
  int br1 = n0 + srow + 64;
  if (NTAIL) br1 = min(br1, N - 1);
  const unsigned short* Br2 = Bt + (long long)br1 * lda + scol;

  auto STAGE = [&](int buf, int s) {
    const int kh = SPLIT ? s * 32 : s * 64;
    const int kl = SPLIT ? K + s * 32 : s * 64 + 32;
    unsigned short* L = lds[buf];
    gload16(Ar + kh, &L[wave * 512]);
    gload16(Ar + (long long)64 * lda + kh, &L[2048 + wave * 512]);
    gload16(Ar + kl, &L[APL + wave * 512]);
    gload16(Ar + (long long)64 * lda + kl, &L[APL + 2048 + wave * 512]);
    gload16(Br + kh, &L[2 * APL + wave * 512]);
    gload16(Br + kl, &L[2 * APL + BPL + wave * 512]);
    if (BN == 128) {
      gload16(Br2 + kh, &L[2 * APL + 2048 + wave * 512]);
      gload16(Br2 + kl, &L[2 * APL + BPL + 2048 + wave * 512]);
    }
  };

  f32x4 acc[4][FN];
  #pragma unroll
  for (int m = 0; m < 4; ++m)
    #pragma unroll
    for (int n = 0; n < FN; ++n) acc[m][n] = (f32x4){0.f, 0.f, 0.f, 0.f};

  STAGE(0, 0);
  int cur = 0;
  for (int s = 0; s < NS; ++s) {
    if (s + 1 < NS) {
      STAGE(cur ^ 1, s + 1);     // 2*LPS outstanding (prev + next)
      if constexpr (BN == 128)
        asm volatile("s_waitcnt vmcnt(8)" ::: "memory");   // prev stage landed
      else
        asm volatile("s_waitcnt vmcnt(6)" ::: "memory");
    } else {
      asm volatile("s_waitcnt vmcnt(0)" ::: "memory");     // last stage
    }
    __builtin_amdgcn_sched_barrier(0);
    __builtin_amdgcn_s_barrier();          // all waves' stage-s data in LDS
    const unsigned short* L = lds[cur];
    half8 bfh[FN], bfl[FN];
    #pragma unroll
    for (int n = 0; n < FN; ++n) {
      int bo = (wn * (FN * 16) + n * 16 + (lane & 15)) * 32 + (lane >> 4) * 8;
      bfh[n] = *(const half8*)&L[2 * APL + bo];
      bfl[n] = *(const half8*)&L[2 * APL + BPL + bo];
    }
    __builtin_amdgcn_s_setprio(1);
    #pragma unroll
    for (int m = 0; m < 4; ++m) {
      int ao = (wm * 64 + m * 16 + (lane & 15)) * 32 + (lane >> 4) * 8;
      half8 afh = *(const half8*)&L[ao];
      half8 afl = *(const half8*)&L[APL + ao];
      #pragma unroll
      for (int n = 0; n < FN; ++n) {
        acc[m][n] = __builtin_amdgcn_mfma_f32_16x16x32_f16(afh, bfh[n], acc[m][n], 0, 0, 0);
        if (SPLIT) {
          acc[m][n] = __builtin_amdgcn_mfma_f32_16x16x32_f16(afl, bfh[n], acc[m][n], 0, 0, 0);
          acc[m][n] = __builtin_amdgcn_mfma_f32_16x16x32_f16(afh, bfl[n], acc[m][n], 0, 0, 0);
        } else {
          acc[m][n] = __builtin_amdgcn_mfma_f32_16x16x32_f16(afl, bfl[n], acc[m][n], 0, 0, 0);
        }
      }
    }
    __builtin_amdgcn_s_setprio(0);
    __builtin_amdgcn_sched_barrier(0);
    __builtin_amdgcn_s_barrier();          // reads retired (in regs) -> next overwrite safe
    cur ^= 1;
  }
  #pragma unroll
  for (int m = 0; m < 4; ++m)
    #pragma unroll
    for (int n = 0; n < FN; ++n) {
      int col = n0 + wn * (FN * 16) + n * 16 + (lane & 15);
      if (!NTAIL || col < N) {
        #pragma unroll
        for (int j = 0; j < 4; ++j) {
          long long row = m0 + wm * 64 + m * 16 + (lane >> 4) * 4 + j;
          long long o = co + row * ldc + col;
          float v = acc[m][n][j];
          if (ADD) v += Add[o];
          C[o] = v;
        }
      }
    }
}

// ---------------- host launch ----------------

extern "C" void kernel_launch(void* const* d_in, const int* in_sizes, int n_in,
                              void* d_out, int out_size, void* d_ws, size_t ws_size,
                              hipStream_t stream) {
  (void)in_sizes; (void)n_in; (void)out_size; (void)ws_size;
  const int*   idx   = (const int*)d_in[0];
  const float* wte   = (const float*)d_in[1];
  const float* wqkv  = (const float*)d_in[2];
  const float* qnw   = (const float*)d_in[3];
  const float* knw   = (const float*)d_in[4];
  const float* oproj = (const float*)d_in[5];
  const float* ffnw  = (const float*)d_in[6];
  const float* gatew = (const float*)d_in[7];
  const float* w13   = (const float*)d_in[8];
  const float* w2p   = (const float*)d_in[9];
  const float* lnf   = (const float*)d_in[10];
  float* out = (float*)d_out;

  char* base = (char*)d_ws;
  size_t off = 0;
  auto alloc = [&](size_t bytes) -> char* {
    off = (off + 255) & ~(size_t)255;
    char* p = base + off; off += bytes; return p;
  };
  float* x     = (float*)alloc((size_t)Ntok * 768 * 4);
  float* qkv   = (float*)alloc((size_t)Ntok * 2304 * 4);
  float* hbuf  = (float*)alloc((size_t)Ntok * 768 * 4);
  float* ffn   = (float*)alloc((size_t)Ntok * 768 * 4);
  unsigned short* x16   = (unsigned short*)alloc((size_t)Ntok * 1536 * 2);
  unsigned short* yfl16 = (unsigned short*)alloc((size_t)Ntok * 1536 * 2);
  unsigned short* qr16  = (unsigned short*)alloc((size_t)24 * 1024 * 128 * 2);
  unsigned short* kr16  = (unsigned short*)alloc((size_t)24 * 1024 * 128 * 2);
  unsigned short* vr16  = (unsigned short*)alloc((size_t)24 * 64 * 2048 * 2);
  unsigned short* xb16  = (unsigned short*)alloc((size_t)Ec * CAPPc * 1536 * 2);
  unsigned short* wo16  = (unsigned short*)alloc((size_t)768 * 1536 * 2);
  unsigned short* xf16  = (unsigned short*)alloc((size_t)Ntok * 768 * 2);
  char* spb = alloc((size_t)24 * 1024 * 1024 * 4);           // scratch region
  float* gu   = (float*)spb;                                 // [0, 50.3M)
  float* yexp = (float*)spb;                                 // [0, 9.4M) over dead gu
  unsigned short* act16 = (unsigned short*)(spb + 50331648); // [50.3M, 75.5M)
  unsigned short* wq16  = (unsigned short*)(spb + 75497472); // [75.5M, 82.6M)
  unsigned short* w13_16 = (unsigned short*)alloc((size_t)Ec * 4096 * 1536 * 2); // 100.66MB
  unsigned short* wt16   = w13_16;                           // alias (used after)
  unsigned short* w2_16  = (unsigned short*)alloc((size_t)Ec * 768 * 4096 * 2);  // 50.3MB
  int* top    = (int*)alloc(Ntok * 4);
  int* rankb  = (int*)alloc(Ntok * 4);
  int* cnt    = (int*)alloc(Lc * Ec * 4);
  float* psum = (float*)alloc(Lc * Ec * 4);
  float* z2   = (float*)alloc(Lc * 4);

  zero_small<<<1, 64, 0, stream>>>(psum, z2);
  embed_k<<<Ntok, 192, 0, stream>>>(idx, wte, x, x16);

  for (int l = 0; l < Lc; ++l) {
    split2_wT<1><<<dim3(72, 24, 1), 256, 0, stream>>>(wqkv + (size_t)l * 768 * 2304, wq16,
                                                      768, 2304, 0, 0);
    split2_wT<1><<<dim3(24, 24, 1), 256, 0, stream>>>(oproj + (size_t)l * 768 * 768, wo16,
                                                      768, 768, 0, 0);
    if (l == 0) {
      split2_wT<1><<<dim3(128, 24, 8), 256, 0, stream>>>(w13, w13_16,
          768, 4096, (long long)768 * 4096, (long long)4096 * 1536);
      split2_wT<1><<<dim3(24, 64, 8), 256, 0, stream>>>(w2p, w2_16,
          2048, 768, (long long)2048 * 768, (long long)768 * 4096);
    } else {
      split2_wT<0><<<dim3(128, 24, 8), 256, 0, stream>>>(w13 + (size_t)Ec * 768 * 4096, w13_16,
          768, 4096, (long long)768 * 4096, (long long)4096 * 768);
      split2_wT<0><<<dim3(24, 64, 8), 256, 0, stream>>>(w2p + (size_t)Ec * 2048 * 768, w2_16,
          2048, 768, (long long)2048 * 768, (long long)768 * 2048);
    }
    // qkv = x @ wqkv[l]
    gemm_h<128, 1, 0, 0><<<288, 256, 0, stream>>>(
        x16, wq16, qkv, nullptr, 2048, 2304, 768, 2304, 16, 18, 0, 0, 1, 0, 0);
    // fused q/k rmsnorm + rope + V transpose
    qk_rope<<<Ntok, 256, 0, stream>>>(qkv, qnw + l * 768, knw + l * 768, qr16, kr16, vr16);
    // fused attention -> yfl16 (split-fp16)
    flash_attn<<<384, 256, 0, stream>>>(qr16, kr16, vr16, yfl16);
    // h = x + y @ o_proj[l]
    gemm_h<64, 1, 1, 0><<<192, 256, 0, stream>>>(
        yfl16, wo16, hbuf, x, 2048, 768, 768, 768, 16, 12, 0, 0, 1, 0, 0);
    rmsnorm_k<<<Ntok, 256, 0, stream>>>(hbuf, 768, ffn, 768, ffnw + l * 768);
    gate_k<<<Ntok / 256, 256, 0, stream>>>(ffn, gatew + (size_t)l * 768 * 8, top,
                                           psum + l * 8, z2 + l);
    route_scan<<<1, 64, 0, stream>>>(top, rankb, cnt + l * 8);
    if (l == 0) {
      scatter_xb<1><<<Ntok, 192, 0, stream>>>(ffn, top, rankb, xb16);
      gemm_h<128, 1, 0, 0><<<768, 256, 0, stream>>>(
          xb16, w13_16, gu, nullptr, 384, 4096, 768, 4096, 3, 32,
          (long long)384 * 1536, (long long)4096 * 1536, 1, (long long)384 * 4096, 0);
      silu_k<1><<<(Ec * CAPPc * Hc) / 256, 256, 0, stream>>>(gu, act16);
      gemm_h<64, 1, 0, 0><<<288, 256, 0, stream>>>(
          act16, w2_16, yexp, nullptr, 384, 768, 2048, 768, 3, 12,
          (long long)384 * 4096, (long long)768 * 4096, 1, (long long)384 * 768, 0);
    } else {
      scatter_xb<0><<<Ntok, 192, 0, stream>>>(ffn, top, rankb, xb16);
      gemm_h<128, 0, 0, 0><<<768, 256, 0, stream>>>(
          xb16, w13_16, gu, nullptr, 384, 4096, 768, 4096, 3, 32,
          (long long)384 * 768, (long long)4096 * 768, 1, (long long)384 * 4096, 0);
      silu_k<0><<<(Ec * CAPPc * Hc) / 256, 256, 0, stream>>>(gu, act16);
      gemm_h<64, 0, 0, 0><<<288, 256, 0, stream>>>(
          act16, w2_16, yexp, nullptr, 384, 768, 2048, 768, 3, 12,
          (long long)384 * 2048, (long long)768 * 2048, 1, (long long)384 * 768, 0);
    }
    gather_add<<<Ntok, 192, 0, stream>>>(hbuf, yexp, top, rankb, x, x16);
  }

  rmsnorm_h<<<Ntok, 256, 0, stream>>>(x, xf16, lnf);
  f2h4<<<(int)(((long long)Vc * 768 / 4 + 255) / 256), 256, 0, stream>>>(
      wte, wt16, (long long)Vc * 768 / 4);
  // logits = xf @ wte^T  (single fp16, BK=64 pipelined, N tail handled)
  gemm_h<128, 0, 0, 1><<<6288, 256, 0, stream>>>(
      xf16, wt16, out, nullptr, 2048, Vc, 768, Vc, 16, 393, 0, 0, 1, 0, 0);
  aux_fin<<<1, 64, 0, stream>>>(psum, cnt, z2, out + LOGITS_N);
}